// Round 12
// baseline (332.748 us; speedup 1.0000x reference)
//
#include <hip/hip_runtime.h>
#include <hip/hip_bf16.h>
#include <cstdio>

typedef __attribute__((ext_vector_type(8))) short short8;
typedef __attribute__((ext_vector_type(8))) _Float16 half8;
typedef __attribute__((ext_vector_type(2))) __fp16 fp16x2;
typedef __attribute__((ext_vector_type(4))) float f32x4;
typedef __attribute__((ext_vector_type(4))) unsigned int uint4v;
typedef __attribute__((ext_vector_type(2))) unsigned int uint2v;

#if defined(__has_builtin)
#if __has_builtin(__builtin_amdgcn_fdot2) && __has_builtin(__builtin_amdgcn_perm) && __has_builtin(__builtin_amdgcn_cvt_pkrtz)
#define USE_DOT2 1
#endif
#endif

// ---------- bf16/fp16 helpers ----------
__device__ __forceinline__ float bfu2f(unsigned short u) {
    return __uint_as_float(((unsigned)u) << 16);
}
__device__ __forceinline__ unsigned short f2bfu(float f) {   // RNE
    __hip_bfloat16 b = __float2bfloat16(f);
    union { __hip_bfloat16 b; unsigned short u; } cv; cv.b = b;
    return cv.u;
}
__device__ __forceinline__ unsigned short f2hu(float f) {    // fp16 RNE bits
    _Float16 h = (_Float16)f;
    union { _Float16 h; unsigned short u; } cv; cv.h = h;
    return cv.u;
}
__device__ __forceinline__ float hu2f(unsigned short u) {
    union { unsigned short u; _Float16 h; } cv; cv.u = u;
    return (float)cv.h;
}
#ifdef USE_DOT2
__device__ __forceinline__ unsigned pkw(float w0, float w1) {
    union { fp16x2 v; unsigned u; } cv;
    cv.v = __builtin_amdgcn_cvt_pkrtz(w0, w1);
    return cv.u;
}
__device__ __forceinline__ float fdot2acc(unsigned a, unsigned b, float c) {
    union { unsigned u; fp16x2 v; } ua, ub; ua.u = a; ub.u = b;
    return __builtin_amdgcn_fdot2(ua.v, ub.v, c, false);
}
#endif

// ---------- graph/model dims ----------
#define N1 80000
#define N2 16000
#define N3 4096
#define E1 256000
#define E2 65536

// ---------- prep + hist (one launch; int zeroing via hipMemsetAsync) ----------
__global__ void prep_hist(const float* __restrict__ W1s, unsigned short* __restrict__ w1s_pk,
                          const float* __restrict__ W2s, unsigned short* __restrict__ w2s_pk,
                          const float* __restrict__ W1d, const float* __restrict__ a1d,
                          float* __restrict__ v1dT,
                          const float* __restrict__ W2d, const float* __restrict__ a2d,
                          float* __restrict__ v2dT,
                          const float* __restrict__ fW, unsigned short* __restrict__ fw_t3,
                          int PB,
                          const int* __restrict__ ed1i, int* __restrict__ cnt1,
                          const int* __restrict__ ed2i, int* __restrict__ cnt2) {
    const int bid = blockIdx.x;
    if (bid < PB) {
        int i = bid * 256 + threadIdx.x;
        const int S0 = 131072, S1 = 131072, S2 = 8192;
        if (i < S0) {
            int k = i >> 9, n = i & 511;            // [K=256][N=512] row-major, KSB=8
            int n16 = n >> 4, l = n & 15, k32 = k >> 5, qq = (k >> 3) & 3, e = k & 7;
            size_t base = ((size_t)(n16 * 8 + k32)) * 512 + (qq * 16 + l) * 8 + e;
            w1s_pk[base] = f2hu(W1s[i]);
        } else if (i < S0 + S1) {
            int j = i - S0;
            int k = j >> 8, n = j & 255;            // [K=512][N=256] row-major, KSB=16
            int n16 = n >> 4, l = n & 15, k32 = k >> 5, qq = (k >> 3) & 3, e = k & 7;
            size_t base = ((size_t)(n16 * 16 + k32)) * 512 + (qq * 16 + l) * 8 + e;
            w2s_pk[base] = f2hu(W2s[j]);
        } else if (i < S0 + S1 + S2) {
            int j = i - S0 - S1;
            int k = j >> 6, n = j & 63;             // K=128, N=64 (flat MLP, bf16 hi/lo)
            float v = fW[j];
            unsigned short h = f2bfu(v);
            unsigned short l = f2bfu(v - bfu2f(h));
            size_t base = (size_t)n * 384;
            fw_t3[base + k] = h;
            fw_t3[base + 128 + k] = l;
            fw_t3[base + 256 + k] = h;
        } else {
            int j = i - S0 - S1 - S2;
            if (j < 2048) {                          // v1dT [8][256]
                int h = j >> 8, k = j & 255;
                float s = 0.f;
                for (int c = 0; c < 64; c++) s += W1d[k * 512 + h * 64 + c] * a1d[h * 64 + c];
                v1dT[j] = s;
            } else if (j < 4096) {                   // v2dT [4][512]
                int jj = j - 2048;
                int h = jj >> 9, k = jj & 511;
                float s = 0.f;
                for (int c = 0; c < 64; c++) s += W2d[k * 256 + h * 64 + c] * a2d[h * 64 + c];
                v2dT[jj] = s;
            }
        }
    } else {
        int i = (bid - PB) * 256 + threadIdx.x;
        if (i < E1) {
            int d = ed1i[i];
            if ((unsigned)d < (unsigned)N2) atomicAdd(&cnt1[d], 1);
        } else if (i < E1 + E2) {
            int d = ed2i[i - E1];
            if ((unsigned)d < (unsigned)N3) atomicAdd(&cnt2[d], 1);
        }
    }
}

__global__ __launch_bounds__(1024)
void scan_dual(const int* __restrict__ c1, int* __restrict__ s1, int Nd1,
               const int* __restrict__ c2, int* __restrict__ s2, int Nd2) {
    const int* cnt = (blockIdx.x == 0) ? c1 : c2;
    int* start = (blockIdx.x == 0) ? s1 : s2;
    int Nd = (blockIdx.x == 0) ? Nd1 : Nd2;
    __shared__ int part[1024];
    int t = threadIdx.x;
    int k = (Nd + 1023) >> 10;
    int lo = t * k, hi = min(lo + k, Nd);
    if (lo > Nd) lo = Nd;
    int s = 0;
    for (int i = lo; i < hi; i++) s += cnt[i];
    part[t] = s;
    __syncthreads();
    for (int off = 1; off < 1024; off <<= 1) {
        int v = (t >= off) ? part[t - off] : 0;
        __syncthreads();
        part[t] += v;
        __syncthreads();
    }
    int run = (t > 0) ? part[t - 1] : 0;
    for (int i = lo; i < hi; i++) { start[i] = run; run += cnt[i]; }
    if (t == 1023) start[Nd] = part[1023];
}

__device__ __forceinline__ void fill_core(int fb,
        const int* __restrict__ sa1, const int* __restrict__ da1,
        const int* __restrict__ st1, int* __restrict__ cu1, int* __restrict__ cs1,
        const int* __restrict__ sa2, const int* __restrict__ da2,
        const int* __restrict__ st2, int* __restrict__ cu2, int* __restrict__ cs2) {
    int i = fb * 256 + threadIdx.x;
    const int *sa, *da, *st;
    int *cu, *cs;
    int Nd, Ns, e;
    if (i < E1) { sa = sa1; da = da1; st = st1; cu = cu1; cs = cs1; Nd = N2; Ns = N1; e = i; }
    else if (i < E1 + E2) { sa = sa2; da = da2; st = st2; cu = cu2; cs = cs2; Nd = N3; Ns = N2; e = i - E1; }
    else return;
    int d = da[e];
    if ((unsigned)d >= (unsigned)Nd) return;
    int p = atomicAdd(&cu[d], 1);
    int idx = st[d] + p;
    if (idx >= st[d + 1]) return;
    int s = sa[e];
    if ((unsigned)s >= (unsigned)Ns) s = 0;
    cs[idx] = s;
}

// ---------- ed precompute cores (ride in GEMM launches) ----------
// ed1[d,h] = x[d,:256] . v1dT[h,:]; one wave per node, fully coalesced row load.
__device__ __forceinline__ void ed1_core(const float* __restrict__ x, const float* __restrict__ v1dT,
                                         float* __restrict__ ed1, int blk) {
    const int lane = threadIdx.x & 63;
    const int w = threadIdx.x >> 6;
    float4 vv[8];
#pragma unroll
    for (int h = 0; h < 8; h++) vv[h] = *(const float4*)&v1dT[h * 256 + lane * 4];
    for (int i = 0; i < 4; i++) {
        int d = blk * 16 + w * 4 + i;
        if (d >= N2) return;
        float4 xv = *(const float4*)&x[(size_t)d * 256 + lane * 4];
        float p[8];
#pragma unroll
        for (int h = 0; h < 8; h++)
            p[h] = xv.x * vv[h].x + xv.y * vv[h].y + xv.z * vv[h].z + xv.w * vv[h].w;
#pragma unroll
        for (int off = 1; off < 64; off <<= 1)
#pragma unroll
            for (int h = 0; h < 8; h++) p[h] += __shfl_xor(p[h], off);
        if (lane < 8) {
            int hh = lane;
            float a01 = (hh & 1) ? p[1] : p[0], a23 = (hh & 1) ? p[3] : p[2];
            float a45 = (hh & 1) ? p[5] : p[4], a67 = (hh & 1) ? p[7] : p[6];
            float b0 = (hh & 2) ? a23 : a01, b1 = (hh & 2) ? a67 : a45;
            ed1[d * 8 + hh] = (hh & 4) ? b1 : b0;
        }
    }
}
// ed2[d,h] = acc1h[d,:512](fp16) . v2dT[h,:]
__device__ __forceinline__ void ed2_core(const unsigned short* __restrict__ xh,
                                         const float* __restrict__ v2dT,
                                         float* __restrict__ ed2, int blk) {
    const int lane = threadIdx.x & 63;
    const int w = threadIdx.x >> 6;
    float vv[4][8];
#pragma unroll
    for (int h = 0; h < 4; h++)
#pragma unroll
        for (int j = 0; j < 8; j++) vv[h][j] = v2dT[h * 512 + lane * 8 + j];
    for (int i = 0; i < 4; i++) {
        int d = blk * 16 + w * 4 + i;
        if (d >= N3) return;
        uint4v rw = *(const uint4v*)&xh[(size_t)d * 512 + lane * 8];
        const unsigned short* rb = (const unsigned short*)&rw;
        float xf[8];
#pragma unroll
        for (int j = 0; j < 8; j++) xf[j] = hu2f(rb[j]);
        float p[4];
#pragma unroll
        for (int h = 0; h < 4; h++) {
            float s = 0.f;
#pragma unroll
            for (int j = 0; j < 8; j++) s += xf[j] * vv[h][j];
            p[h] = s;
        }
#pragma unroll
        for (int off = 1; off < 64; off <<= 1)
#pragma unroll
            for (int h = 0; h < 4; h++) p[h] += __shfl_xor(p[h], off);
        if (lane < 4) {
            int hh = lane;
            float a01 = (hh & 1) ? p[1] : p[0], a23 = (hh & 1) ? p[3] : p[2];
            ed2[d * 4 + hh] = (hh & 2) ? a23 : a01;
        }
    }
}

// ---------- fp16 MFMA GEMM core, LDS-shared A, K-step 64; 2-deep A prefetch ----------
// C-store: LDS transpose epilogue -> 16B/lane coalesced stores (8 vector stores per
// thread instead of 64 scalar 2B stores).
template <bool AF16>
__device__ __forceinline__ void gemm_core(_Float16 (*As)[64][72],
              const void* __restrict__ Ax,
              const unsigned short* __restrict__ Bp, unsigned short* __restrict__ C,
              const float* __restrict__ att, float* __restrict__ es_out,
              int MT, int NB, int N, int K, int H, int hb) {
    const int xcd = hb & 7;
    const int sI = hb >> 3;
    const int mt = (sI / NB) * 8 + xcd;
    const int nb = sI % NB;
    if (mt >= MT) return;
    const int m0 = mt * 64;
    const int tid = threadIdx.x;
    const int wave = tid >> 6, lane = tid & 63;
    const int q = lane >> 4, l15 = lane & 15;
    const int n0 = nb * 256 + wave * 64;
    const int KS = K >> 6;
    const int KSB = K >> 5;
    const int arow = tid >> 2, ac16 = (tid & 3) * 16;
    const unsigned short* Bbase = Bp + (size_t)(n0 >> 4) * KSB * 512 + lane * 8;

    f32x4 acc[4][4] = {};
    half8 b[2][4];
    // staging reg sets (only the relevant dtype's set is live)
    float4 sA0, sA1, sA2, sA3, sB0, sB1, sB2, sB3;
    half8 hA0, hA1, hB0, hB1;

    auto loadS = [&](int t, int which) {   // which: 0 -> set A, 1 -> set B (literal)
        if constexpr (AF16) {
            const _Float16* p = (const _Float16*)Ax + (size_t)(m0 + arow) * K + t * 64 + ac16;
            if (which == 0) { hA0 = *(const half8*)p; hA1 = *(const half8*)(p + 8); }
            else            { hB0 = *(const half8*)p; hB1 = *(const half8*)(p + 8); }
        } else {
            const float* p = (const float*)Ax + (size_t)(m0 + arow) * K + t * 64 + ac16;
            if (which == 0) {
                sA0 = *(const float4*)p;       sA1 = *(const float4*)(p + 4);
                sA2 = *(const float4*)(p + 8); sA3 = *(const float4*)(p + 12);
            } else {
                sB0 = *(const float4*)p;       sB1 = *(const float4*)(p + 4);
                sB2 = *(const float4*)(p + 8); sB3 = *(const float4*)(p + 12);
            }
        }
    };
    auto writeS = [&](int buf, int which) {
        half8 v0, v1;
        if constexpr (AF16) {
            if (which == 0) { v0 = hA0; v1 = hA1; } else { v0 = hB0; v1 = hB1; }
        } else {
            float4 t0, t1, t2, t3;
            if (which == 0) { t0 = sA0; t1 = sA1; t2 = sA2; t3 = sA3; }
            else            { t0 = sB0; t1 = sB1; t2 = sB2; t3 = sB3; }
            v0[0] = (_Float16)t0.x; v0[1] = (_Float16)t0.y;
            v0[2] = (_Float16)t0.z; v0[3] = (_Float16)t0.w;
            v0[4] = (_Float16)t1.x; v0[5] = (_Float16)t1.y;
            v0[6] = (_Float16)t1.z; v0[7] = (_Float16)t1.w;
            v1[0] = (_Float16)t2.x; v1[1] = (_Float16)t2.y;
            v1[2] = (_Float16)t2.z; v1[3] = (_Float16)t2.w;
            v1[4] = (_Float16)t3.x; v1[5] = (_Float16)t3.y;
            v1[6] = (_Float16)t3.z; v1[7] = (_Float16)t3.w;
        }
        *(half8*)&As[buf][arow][ac16] = v0;
        *(half8*)&As[buf][arow][ac16 + 8] = v1;
    };
    auto loadB = [&](int k32, int kh, int nt) {
        b[kh][nt] = *(const half8*)(Bbase + ((size_t)nt * KSB + k32) * 512);
    };
    auto mstep = [&](int bufi, int tn) {   // MFMAs on buf; reload B for step tn (if >=0)
#pragma unroll
        for (int kh = 0; kh < 2; kh++)
#pragma unroll
            for (int rg = 0; rg < 4; rg++) {
                half8 a = *(const half8*)&As[bufi][rg * 16 + l15][kh * 32 + q * 8];
#pragma unroll
                for (int nt = 0; nt < 4; nt++) {
                    acc[rg][nt] = __builtin_amdgcn_mfma_f32_16x16x32_f16(a, b[kh][nt], acc[rg][nt], 0, 0, 0);
                    if (rg == 3 && tn >= 0) loadB(2 * tn + kh, kh, nt);
                }
            }
    };

    // prologue: A0 and A1 in flight; B0 frags; write A0; sync
    loadS(0, 0);
    if (KS > 1) loadS(1, 1);
#pragma unroll
    for (int kh = 0; kh < 2; kh++)
#pragma unroll
        for (int nt = 0; nt < 4; nt++) loadB(kh, kh, nt);
    writeS(0, 0);
    __syncthreads();

    // KS is even (4 or 8): even steps read buf0, odd steps read buf1
    for (int t = 0; t < KS; t += 2) {
        if (t + 2 < KS) loadS(t + 2, 0);          // issue A(t+2): 2 phases of cover
        mstep(0, (t + 1 < KS) ? t + 1 : -1);
        if (t + 1 < KS) {
            writeS(1, 1);                          // A(t+1) from set B -> buf1
            __syncthreads();
            if (t + 3 < KS) loadS(t + 3, 1);       // issue A(t+3)
            mstep(1, (t + 2 < KS) ? t + 2 : -1);
            if (t + 2 < KS) {
                writeS(0, 0);                      // A(t+2) from set A -> buf0
                __syncthreads();
            }
        }
    }

    // fused escore (reads acc; before the transpose reuses LDS)
    {
        const int head = n0 >> 6;
        float av[4];
#pragma unroll
        for (int nt = 0; nt < 4; nt++) av[nt] = att[head * 64 + nt * 16 + l15];
#pragma unroll
        for (int rg = 0; rg < 4; rg++)
#pragma unroll
            for (int r = 0; r < 4; r++) {
                float p = acc[rg][0][r] * av[0] + acc[rg][1][r] * av[1]
                        + acc[rg][2][r] * av[2] + acc[rg][3][r] * av[3];
#pragma unroll
                for (int off = 1; off < 16; off <<= 1) p += __shfl_xor(p, off);
                if (l15 == 0)
                    es_out[(size_t)(m0 + rg * 16 + q * 4 + r) * H + head] = p;
            }
    }

    // C-store: LDS transpose, 2 half-tiles of 32 rows x 256 cols; 16B/lane stores
    {
        _Float16 (*Tr)[264] = (_Float16 (*)[264]) & As[0][0][0];   // 32*264*2 = 16896B <= 18432B
        const int cb = nb * 256;
        const int trow = tid >> 3, tchk = tid & 7;
#pragma unroll
        for (int hrg = 0; hrg < 2; hrg++) {
            __syncthreads();   // previous LDS use (K-loop frags / prior half reads) done
#pragma unroll
            for (int rg2 = 0; rg2 < 2; rg2++)
#pragma unroll
                for (int nt = 0; nt < 4; nt++)
#pragma unroll
                    for (int r = 0; r < 4; r++)
                        Tr[rg2 * 16 + q * 4 + r][wave * 64 + nt * 16 + l15] =
                            (_Float16)acc[hrg * 2 + rg2][nt][r];
            __syncthreads();
            _Float16* dp = (_Float16*)&C[(size_t)(m0 + hrg * 32 + trow) * N + cb + tchk * 32];
            const _Float16* sp = &Tr[trow][tchk * 32];
#pragma unroll
            for (int i = 0; i < 4; i++)
                *(half8*)(dp + i * 8) = *(const half8*)(sp + i * 8);
        }
    }
}

// ---------- layer-1 launch: GEMM + fill + ed1 ----------
__global__ __launch_bounds__(256, 2)
void gemm1_fused(const void* __restrict__ Ax,
                 const unsigned short* __restrict__ Bp, unsigned short* __restrict__ C,
                 const float* __restrict__ att, float* __restrict__ es_out,
                 int MT, int NB, int N, int K, int H, int G1, int FB,
                 const int* sa1, const int* da1, const int* st1, int* cu1, int* cs1,
                 const int* sa2, const int* da2, const int* st2, int* cu2, int* cs2,
                 const float* __restrict__ xe, const float* __restrict__ v1dT,
                 float* __restrict__ ed1) {
    __shared__ alignas(16) _Float16 As[2][64][72];
    const int bid = blockIdx.x;
    if (bid < G1) gemm_core<false>(As, Ax, Bp, C, att, es_out, MT, NB, N, K, H, bid);
    else if (bid < G1 + FB) fill_core(bid - G1, sa1, da1, st1, cu1, cs1, sa2, da2, st2, cu2, cs2);
    else ed1_core(xe, v1dT, ed1, bid - G1 - FB);
}

// ---------- flat MLP core (64x64 tile, Bt3 bf16 hi/lo, fp32 A in-kernel split) ----------
__device__ __forceinline__ void flat_core(unsigned char* smemraw,
        const float* __restrict__ A, const unsigned short* __restrict__ Bt3,
        float* __restrict__ C, int mb) {
    const int K = 128, N = 64, KK = 384;
    auto As = (unsigned short (*)[64][72])smemraw;
    auto Bs = (unsigned short (*)[72])(smemraw + 18432);
    const int tid = threadIdx.x;
    const int wave = tid >> 6, lane = tid & 63;
    const int wr = wave >> 1, wc = wave & 1;
    const int quad = lane >> 4, l15 = lane & 15;
    const int m0 = mb * 64, n0 = 0;
    f32x4 acc[2][2] = {};
    for (int k0 = 0; k0 < KK; k0 += 64) {
        const int seg = k0 / K;
        const int ks = k0 - seg * K;
#pragma unroll
        for (int i = 0; i < 2; i++) {
            int idx = tid + i * 256;
            int r = idx >> 3, cv = (idx & 7) * 8;
            const float* ap = &A[(size_t)(m0 + r) * K + ks + cv];
            const float4 v0 = *(const float4*)ap;
            const float4 v1 = *(const float4*)(ap + 4);
            float va[8] = {v0.x, v0.y, v0.z, v0.w, v1.x, v1.y, v1.z, v1.w};
            short8 h8, l8;
#pragma unroll
            for (int j = 0; j < 8; j++) {
                unsigned short hh = f2bfu(va[j]);
                h8[j] = (short)hh;
                l8[j] = (short)f2bfu(va[j] - bfu2f(hh));
            }
            *(short8*)&As[0][r][cv] = h8;
            *(short8*)&As[1][r][cv] = l8;
            *(short8*)&Bs[r][cv] = *(const short8*)&Bt3[(size_t)(n0 + r) * KK + k0 + cv];
        }
        __syncthreads();
        const int abank = (seg < 2) ? 0 : 1;
#pragma unroll
        for (int kk = 0; kk < 64; kk += 32) {
            short8 a[2], b[2];
#pragma unroll
            for (int t = 0; t < 2; t++) {
                a[t] = *(const short8*)&As[abank][wr * 32 + t * 16 + l15][kk + quad * 8];
                b[t] = *(const short8*)&Bs[wc * 32 + t * 16 + l15][kk + quad * 8];
            }
#pragma unroll
            for (int mt = 0; mt < 2; mt++)
#pragma unroll
                for (int nt = 0; nt < 2; nt++)
                    acc[mt][nt] = __builtin_amdgcn_mfma_f32_16x16x32_bf16(
                        a[mt], b[nt], acc[mt][nt], 0, 0, 0);
        }
        __syncthreads();
    }
#pragma unroll
    for (int mt = 0; mt < 2; mt++)
#pragma unroll
        for (int nt = 0; nt < 2; nt++)
#pragma unroll
            for (int r = 0; r < 4; r++) {
                int row = m0 + wr * 32 + mt * 16 + quad * 4 + r;
                int col = n0 + wc * 32 + nt * 16 + l15;
                C[(size_t)row * N + col] = acc[mt][nt][r];
            }
}

// ---------- layer-2 launch: GEMM + flat MLP + ed2 ----------
__global__ __launch_bounds__(256, 2)
void gemm2_fused(const void* __restrict__ Ax,
                 const unsigned short* __restrict__ Bp, unsigned short* __restrict__ C,
                 const float* __restrict__ att, float* __restrict__ es_out,
                 int MT, int NB, int N, int K, int H, int G2, int FLB,
                 const float* __restrict__ fA, const unsigned short* __restrict__ fBt3,
                 float* __restrict__ fC,
                 const unsigned short* __restrict__ x2h, const float* __restrict__ v2dT,
                 float* __restrict__ ed2) {
    __shared__ alignas(16) unsigned char smem[27648];
    const int bid = blockIdx.x;
    if (bid < G2) gemm_core<true>((_Float16(*)[64][72])smem, Ax, Bp, C, att, es_out,
                                  MT, NB, N, K, H, bid);
    else if (bid < G2 + FLB) flat_core(smem, fA, fBt3, fC, bid - G2);
    else ed2_core(x2h, v2dT, ed2, bid - G2 - FLB);
}

// ---------- GAT aggregate v3: csr-once + shfl distribution + fp16 dot2 gather ----------
// One wave per dst node. edh from precomputed edv (1 load). Neighbor list loaded once
// coalesced into regs (fast path n<=64 for H=8, n<=128 for H=4); alpha es loads batched;
// gather chunks software-pipelined with double reg-buffers; rows fp16, inner loop
// v_perm + v_dot2_f32_f16 (2 rows per op). FIN: fused output head.
template <int H, bool ELU, bool HOUT, bool FIN>
__global__ __launch_bounds__(256)
void gat_agg3(const int* __restrict__ csr, const int* __restrict__ rs,
              const unsigned short* __restrict__ hs,  // [Ns, H*64] fp16
              const float* __restrict__ es,           // [Ns, H]
              const float* __restrict__ edv,          // [Nd, H]
              const float* __restrict__ bias,
              void* __restrict__ out, int Nd,
              const float* __restrict__ fbuf, const float* __restrict__ flat_b,
              const float* __restrict__ last, const float* __restrict__ outW,
              const float* __restrict__ outb, float* __restrict__ fout) {
    constexpr int LH = (H == 8) ? 3 : 2;
    constexpr int EPC = 64 >> LH;          // rows per chunk: 8 (H=8) / 16 (H=4)
    constexpr int ND = H / 2;              // dwords per lane row-slice
    const int lane = threadIdx.x & 63;
    const int d = blockIdx.x * 4 + (threadIdx.x >> 6);
    if (d >= Nd) return;
    const int h = lane & (H - 1);
    const int e0 = lane >> LH;
    const int hB = lane >> (6 - LH);
    const float edh = edv[(size_t)d * H + h];
    const int beg = rs[d];
    const int deg = rs[d + 1] - beg;
    const int n = deg + 1;
    const int nch = (n + EPC - 1) / EPC;
    float acc[H] = {};
    const size_t rowoff = (size_t)lane * H;
    if (nch <= 8) {
        // --- neighbor indices: ONE coalesced load per wave ---
        int idxA = d, idxB = d;
        if (lane < deg) idxA = csr[beg + lane];
        if constexpr (H == 4) { if (64 + lane < deg) idxB = csr[beg + 64 + lane]; }
        // --- batched es loads (1 round trip) ---
        float av[8];
#pragma unroll
        for (int c = 0; c < 8; c++) {
            if (c < nch) {
                int jv = c * EPC + e0;
                int s;
                if (c * EPC + EPC - 1 < 64) s = __shfl(idxA, jv);
                else s = __shfl(idxB, jv - 64);
                av[c] = es[(size_t)s * H + h];
            }
        }
        // --- chunk row loads (pipelined, double reg buffer) ---
        unsigned rvA[EPC][ND], rvB[EPC][ND];
        auto loadChunk = [&](int c, unsigned (&rv)[EPC][ND]) {
#pragma unroll
            for (int u = 0; u < EPC; u++) {
                int src = c * EPC + u;
                int s = (src < 64) ? __shfl(idxA, src) : __shfl(idxB, src - 64);
                const unsigned short* rp = &hs[(size_t)s * (H * 64) + rowoff];
                if constexpr (H == 8) *(uint4v*)&rv[u][0] = *(const uint4v*)rp;
                else *(uint2v*)&rv[u][0] = *(const uint2v*)rp;
            }
        };
        loadChunk(0, rvA);   // overlaps softmax below
        // --- softmax from cached alphas ---
        float al[8], mx = -1e30f;
#pragma unroll
        for (int c = 0; c < 8; c++) {
            int jv = c * EPC + e0;
            float a = -1e30f;
            if (c < nch && jv < n) { a = av[c] + edh; a = (a > 0.f) ? a : 0.2f * a; }
            al[c] = a;
            mx = fmaxf(mx, a);
        }
#pragma unroll
        for (int off = H; off < 64; off <<= 1) mx = fmaxf(mx, __shfl_xor(mx, off));
        float exv[8], den = 0.f;
#pragma unroll
        for (int c = 0; c < 8; c++) { exv[c] = expf(al[c] - mx); den += exv[c]; }
#pragma unroll
        for (int off = H; off < 64; off <<= 1) den += __shfl_xor(den, off);
        const float inv = 1.f / den;
        float ec[8];
#pragma unroll
        for (int c = 0; c < 8; c++) ec[c] = exv[c] * inv;
        // --- gather: guard-free, paired-row dot2 ---
        auto computeChunk = [&](int c, unsigned (&rv)[EPC][ND]) {
#pragma unroll
            for (int pu = 0; pu < EPC / 2; pu++) {
                float w0 = __shfl(ec[c], (2 * pu) * H + hB);
                float w1 = __shfl(ec[c], (2 * pu + 1) * H + hB);
#ifdef USE_DOT2
                unsigned w2 = pkw(w0, w1);
#pragma unroll
                for (int dwi = 0; dwi < ND; dwi++) {
                    unsigned lo = __builtin_amdgcn_perm(rv[2 * pu + 1][dwi], rv[2 * pu][dwi], 0x05040100u);
                    unsigned hi = __builtin_amdgcn_perm(rv[2 * pu + 1][dwi], rv[2 * pu][dwi], 0x07060302u);
                    acc[2 * dwi] = fdot2acc(w2, lo, acc[2 * dwi]);
                    acc[2 * dwi + 1] = fdot2acc(w2, hi, acc[2 * dwi + 1]);
                }
#else
#pragma unroll
                for (int dwi = 0; dwi < ND; dwi++) {
                    unsigned q0 = rv[2 * pu][dwi], q1 = rv[2 * pu + 1][dwi];
                    acc[2 * dwi]     += w0 * hu2f((unsigned short)(q0 & 0xffff))
                                      + w1 * hu2f((unsigned short)(q1 & 0xffff));
                    acc[2 * dwi + 1] += w0 * hu2f((unsigned short)(q0 >> 16))
                                      + w1 * hu2f((unsigned short)(q1 >> 16));
                }
#endif
            }
        };
#pragma unroll
        for (int c = 0; c < 8; c += 2) {
            if (c >= nch) break;
            if (c + 1 < nch) loadChunk(c + 1, rvB);
            computeChunk(c, rvA);
            if (c + 1 >= nch) break;
            if (c + 2 < nch) loadChunk(c + 2, rvA);
            computeChunk(c + 1, rvB);
        }
    } else {
        // fallback two-pass (very rare large-degree nodes)
        float mx = -1e30f;
        for (int j0 = 0; j0 < n; j0 += EPC) {
            int j = j0 + e0;
            if (j < n) {
                int s = (j < deg) ? csr[beg + j] : d;
                float a = es[(size_t)s * H + h] + edh;
                a = (a > 0.0f) ? a : 0.2f * a;
                mx = fmaxf(mx, a);
            }
        }
#pragma unroll
        for (int off = H; off < 64; off <<= 1) mx = fmaxf(mx, __shfl_xor(mx, off));
        float den = 0.0f;
        for (int j0 = 0; j0 < n; j0 += EPC) {
            int j = j0 + e0;
            if (j < n) {
                int s = (j < deg) ? csr[beg + j] : d;
                float a = es[(size_t)s * H + h] + edh;
                a = (a > 0.0f) ? a : 0.2f * a;
                den += expf(a - mx);
            }
        }
#pragma unroll
        for (int off = H; off < 64; off <<= 1) den += __shfl_xor(den, off);
        const float inv = 1.0f / den;
        const float mB = __shfl(mx, hB);
        const float invB = __shfl(inv, hB);
        const float edhB = __shfl(edh, hB);
        for (int j = 0; j < n; j++) {
            int s = (j < deg) ? csr[beg + j] : d;
            const unsigned short* rp = &hs[(size_t)s * (H * 64) + rowoff];
            float a = es[(size_t)s * H + hB] + edhB;
            a = (a > 0.0f) ? a : 0.2f * a;
            float w = expf(a - mB) * invB;
#pragma unroll
            for (int k = 0; k < H; k++) acc[k] += w * hu2f(rp[k]);
        }
    }
    if constexpr (FIN) {
        float f4[4];
#pragma unroll
        for (int k = 0; k < 4; k++) {
            float a2v = acc[k] + __shfl_xor(acc[k], 32);
            f4[k] = a2v + __shfl_xor(a2v, 16);
        }
        float part = 0.f;
        if (lane < 16) {
            const int c0 = lane * 4;
            float4 fb4 = *(const float4*)&fbuf[(size_t)d * 64 + c0];
            float4 lb4 = *(const float4*)&last[(size_t)d * 64 + c0];
            const float* fbv = &fb4.x;
            const float* lbv = &lb4.x;
#pragma unroll
            for (int k = 0; k < 4; k++) {
                int c = c0 + k;
                float h2 = 0.25f * f4[k] + bias[c];
                part += h2 * outW[c];
                part += (fbv[k] + flat_b[c]) * outW[64 + c];
                part += lbv[k] * outW[128 + c];
            }
        }
#pragma unroll
        for (int off = 1; off < 16; off <<= 1) part += __shfl_xor(part, off);
        if (lane == 0) fout[d] = part + outb[0];
    } else {
#pragma unroll
        for (int k = 0; k < H; k++) {
            float v = acc[k];
            if (ELU) {
                v += bias[lane * H + k];
                v = (v > 0.0f) ? v : expm1f(v);
            }
            acc[k] = v;
        }
        if constexpr (HOUT) {
            half8 hv;
#pragma unroll
            for (int k = 0; k < H; k++) hv[k] = (_Float16)acc[k];
            _Float16* op = (_Float16*)out + (size_t)d * (H * 64) + rowoff;
            *(half8*)op = hv;
        } else {
            float* op = (float*)out + (size_t)d * (H * 64) + rowoff;
#pragma unroll
            for (int qd = 0; qd < H / 4; qd++)
                *(float4*)&op[qd * 4] = *(float4*)&acc[qd * 4];
        }
    }
}

extern "C" void kernel_launch(void* const* d_in, const int* in_sizes, int n_in,
                              void* d_out, int out_size, void* d_ws, size_t ws_size,
                              hipStream_t stream) {
    const float* x    = (const float*)d_in[0];
    const float* flat = (const float*)d_in[1];
    const float* last = (const float*)d_in[2];
    const int*  es1i  = (const int*)d_in[3];
    const int*  ed1i  = (const int*)d_in[4];
    const int*  es2i  = (const int*)d_in[5];
    const int*  ed2i  = (const int*)d_in[6];
    const float* W1s  = (const float*)d_in[7];
    const float* W1d  = (const float*)d_in[8];
    const float* a1s  = (const float*)d_in[9];
    const float* a1d  = (const float*)d_in[10];
    const float* b1   = (const float*)d_in[11];
    const float* W2s  = (const float*)d_in[12];
    const float* W2d  = (const float*)d_in[13];
    const float* a2s  = (const float*)d_in[14];
    const float* a2d  = (const float*)d_in[15];
    const float* b2   = (const float*)d_in[16];
    const float* fW   = (const float*)d_in[17];
    const float* fb   = (const float*)d_in[18];
    const float* oW   = (const float*)d_in[19];
    const float* ob   = (const float*)d_in[20];
    float* out = (float*)d_out;

    float* ws = (float*)d_ws;
    // ---- layout (float-element offsets; proven footprint) ----
    unsigned short* hs1_h = (unsigned short*)ws;                   // [80000][512] fp16
    float* es1f = ws + 24576000;                                   // [80000][8]
    float* ed1f = ws + 25216000;                                   // [16000][8]
    float* acc1 = ws + 25344000;                                   // L1 out, fp16 [16000][512]
    unsigned short* wb = (unsigned short*)(ws + 54016000);
    unsigned short* w1s_pk = wb;                                   // 131072 us
    unsigned short* w2s_pk = wb + 524288;                          // 131072 us
    unsigned short* fw_t3  = wb + 1048576;                         // 24576 us
    float* v1dT = ws + 54600000;                                   // 2048
    float* v2dT = ws + 54602048;                                   // 2048
    int* ibase   = (int*)(ws + 54816000);
    int* cnt1    = ibase;
    int* cursor1 = ibase + 16000;
    int* cnt2    = ibase + 32000;
    int* cursor2 = ibase + 36096;
    int* start1  = ibase + 40192;
    int* start2  = ibase + 56193;
    int* csr1    = ibase + 60290;
    int* csr2    = ibase + 316290;
    const size_t NEED = ((size_t)54816000 + 381826) * 4;
    if (ws_size < NEED) {
        fprintf(stderr, "kernel_launch: ws_size %zu < needed %zu\n", ws_size, NEED);
        return;
    }
    unsigned short* hs2_h = (unsigned short*)ws;                   // [16000][256] fp16
    float* es2f = ws + 2572288;
    float* ed2f = ws + 2636288;                                    // [4096][4]
    float* fbuf = ws + 3701248;
    unsigned short* acc1h = (unsigned short*)acc1;

    // ---- zero counters/cursors, then prep+hist (1 launch) + scan ----
    (void)hipMemsetAsync(ibase, 0, 40192 * sizeof(int), stream);
    {
        const int PB = 1072;   // (131072+131072+8192+4096)/256
        const int HB = (E1 + E2) / 256;   // 1256
        prep_hist<<<PB + HB, 256, 0, stream>>>(
            W1s, w1s_pk, W2s, w2s_pk,
            W1d, a1d, v1dT, W2d, a2d, v2dT,
            fW, fw_t3, PB, ed1i, cnt1, ed2i, cnt2);
    }
    scan_dual<<<2, 1024, 0, stream>>>(cnt1, start1, N2, cnt2, start2, N3);

    // ---- layer 1 GEMM + CSR fill + ed1 in one launch ----
    {
        const int MT = N1 / 64;             // 1250
        const int NB = 2;
        const int G1 = 8 * NB * ((MT + 7) / 8);   // 2512
        const int FB = (E1 + E2) / 256;           // 1256
        const int EB = N2 / 16;                   // 1000
        gemm1_fused<<<G1 + FB + EB, 256, 0, stream>>>(
            x, w1s_pk, hs1_h, a1s, es1f, MT, NB, 512, 256, 8, G1, FB,
            es1i, ed1i, start1, cursor1, csr1, es2i, ed2i, start2, cursor2, csr2,
            x, v1dT, ed1f);
    }
    gat_agg3<8, true, true, false><<<N2 / 4, 256, 0, stream>>>(
        csr1, start1, hs1_h, es1f, ed1f, b1, acc1h, N2,
        nullptr, nullptr, nullptr, nullptr, nullptr, nullptr);

    // ---- layer 2 GEMM + flat MLP + ed2 in one launch ----
    {
        const int MT = N2 / 64;             // 250
        const int G2 = 8 * ((MT + 7) / 8);  // 256
        const int FLB = N3 / 64;            // 64
        const int EB2 = N3 / 16;            // 256
        gemm2_fused<<<G2 + FLB + EB2, 256, 0, stream>>>(
            acc1h, w2s_pk, hs2_h, a2s, es2f, MT, 1, 256, 512, 4, G2, FLB,
            flat, fw_t3, fbuf,
            acc1h, v2dT, ed2f);
    }
    // ---- fused agg2 + output head ----
    gat_agg3<4, false, false, true><<<N3 / 4, 256, 0, stream>>>(
        csr2, start2, hs2_h, es2f, ed2f, b2, nullptr, N3,
        fbuf, fb, last, oW, ob, out);
}

// Round 13
// 328.642 us; speedup vs baseline: 1.0125x; 1.0125x over previous
//
#include <hip/hip_runtime.h>
#include <hip/hip_bf16.h>
#include <cstdio>

typedef __attribute__((ext_vector_type(8))) short short8;
typedef __attribute__((ext_vector_type(8))) _Float16 half8;
typedef __attribute__((ext_vector_type(2))) __fp16 fp16x2;
typedef __attribute__((ext_vector_type(4))) float f32x4;
typedef __attribute__((ext_vector_type(4))) unsigned int uint4v;
typedef __attribute__((ext_vector_type(2))) unsigned int uint2v;

#if defined(__has_builtin)
#if __has_builtin(__builtin_amdgcn_fdot2) && __has_builtin(__builtin_amdgcn_perm) && __has_builtin(__builtin_amdgcn_cvt_pkrtz)
#define USE_DOT2 1
#endif
#endif

// ---------- bf16/fp16 helpers ----------
__device__ __forceinline__ float bfu2f(unsigned short u) {
    return __uint_as_float(((unsigned)u) << 16);
}
__device__ __forceinline__ unsigned short f2bfu(float f) {   // RNE
    __hip_bfloat16 b = __float2bfloat16(f);
    union { __hip_bfloat16 b; unsigned short u; } cv; cv.b = b;
    return cv.u;
}
__device__ __forceinline__ unsigned short f2hu(float f) {    // fp16 RNE bits
    _Float16 h = (_Float16)f;
    union { _Float16 h; unsigned short u; } cv; cv.h = h;
    return cv.u;
}
__device__ __forceinline__ float hu2f(unsigned short u) {
    union { unsigned short u; _Float16 h; } cv; cv.u = u;
    return (float)cv.h;
}
#ifdef USE_DOT2
__device__ __forceinline__ unsigned pkw(float w0, float w1) {
    union { fp16x2 v; unsigned u; } cv;
    cv.v = __builtin_amdgcn_cvt_pkrtz(w0, w1);
    return cv.u;
}
__device__ __forceinline__ float fdot2acc(unsigned a, unsigned b, float c) {
    union { unsigned u; fp16x2 v; } ua, ub; ua.u = a; ub.u = b;
    return __builtin_amdgcn_fdot2(ua.v, ub.v, c, false);
}
#endif

// ---------- graph/model dims ----------
#define N1 80000
#define N2 16000
#define N3 4096
#define E1 256000
#define E2 65536

// ---------- prep + hist (one launch; int zeroing via hipMemsetAsync) ----------
__global__ void prep_hist(const float* __restrict__ W1s, unsigned short* __restrict__ w1s_pk,
                          const float* __restrict__ W2s, unsigned short* __restrict__ w2s_pk,
                          const float* __restrict__ W1d, const float* __restrict__ a1d,
                          float* __restrict__ v1dT,
                          const float* __restrict__ W2d, const float* __restrict__ a2d,
                          float* __restrict__ v2dT,
                          const float* __restrict__ fW, unsigned short* __restrict__ fw_t3,
                          int PB,
                          const int* __restrict__ ed1i, int* __restrict__ cnt1,
                          const int* __restrict__ ed2i, int* __restrict__ cnt2) {
    const int bid = blockIdx.x;
    if (bid < PB) {
        int i = bid * 256 + threadIdx.x;
        const int S0 = 131072, S1 = 131072, S2 = 8192;
        if (i < S0) {
            int k = i >> 9, n = i & 511;            // [K=256][N=512] row-major, KSB=8
            int n16 = n >> 4, l = n & 15, k32 = k >> 5, qq = (k >> 3) & 3, e = k & 7;
            size_t base = ((size_t)(n16 * 8 + k32)) * 512 + (qq * 16 + l) * 8 + e;
            w1s_pk[base] = f2hu(W1s[i]);
        } else if (i < S0 + S1) {
            int j = i - S0;
            int k = j >> 8, n = j & 255;            // [K=512][N=256] row-major, KSB=16
            int n16 = n >> 4, l = n & 15, k32 = k >> 5, qq = (k >> 3) & 3, e = k & 7;
            size_t base = ((size_t)(n16 * 16 + k32)) * 512 + (qq * 16 + l) * 8 + e;
            w2s_pk[base] = f2hu(W2s[j]);
        } else if (i < S0 + S1 + S2) {
            int j = i - S0 - S1;
            int k = j >> 6, n = j & 63;             // K=128, N=64 (flat MLP, bf16 hi/lo)
            float v = fW[j];
            unsigned short h = f2bfu(v);
            unsigned short l = f2bfu(v - bfu2f(h));
            size_t base = (size_t)n * 384;
            fw_t3[base + k] = h;
            fw_t3[base + 128 + k] = l;
            fw_t3[base + 256 + k] = h;
        } else {
            int j = i - S0 - S1 - S2;
            if (j < 2048) {                          // v1dT [8][256]
                int h = j >> 8, k = j & 255;
                float s = 0.f;
                for (int c = 0; c < 64; c++) s += W1d[k * 512 + h * 64 + c] * a1d[h * 64 + c];
                v1dT[j] = s;
            } else if (j < 4096) {                   // v2dT [4][512]
                int jj = j - 2048;
                int h = jj >> 9, k = jj & 511;
                float s = 0.f;
                for (int c = 0; c < 64; c++) s += W2d[k * 256 + h * 64 + c] * a2d[h * 64 + c];
                v2dT[jj] = s;
            }
        }
    } else {
        int i = (bid - PB) * 256 + threadIdx.x;
        if (i < E1) {
            int d = ed1i[i];
            if ((unsigned)d < (unsigned)N2) atomicAdd(&cnt1[d], 1);
        } else if (i < E1 + E2) {
            int d = ed2i[i - E1];
            if ((unsigned)d < (unsigned)N3) atomicAdd(&cnt2[d], 1);
        }
    }
}

__global__ __launch_bounds__(1024)
void scan_dual(const int* __restrict__ c1, int* __restrict__ s1, int Nd1,
               const int* __restrict__ c2, int* __restrict__ s2, int Nd2) {
    const int* cnt = (blockIdx.x == 0) ? c1 : c2;
    int* start = (blockIdx.x == 0) ? s1 : s2;
    int Nd = (blockIdx.x == 0) ? Nd1 : Nd2;
    __shared__ int part[1024];
    int t = threadIdx.x;
    int k = (Nd + 1023) >> 10;
    int lo = t * k, hi = min(lo + k, Nd);
    if (lo > Nd) lo = Nd;
    int s = 0;
    for (int i = lo; i < hi; i++) s += cnt[i];
    part[t] = s;
    __syncthreads();
    for (int off = 1; off < 1024; off <<= 1) {
        int v = (t >= off) ? part[t - off] : 0;
        __syncthreads();
        part[t] += v;
        __syncthreads();
    }
    int run = (t > 0) ? part[t - 1] : 0;
    for (int i = lo; i < hi; i++) { start[i] = run; run += cnt[i]; }
    if (t == 1023) start[Nd] = part[1023];
}

__device__ __forceinline__ void fill_core(int fb,
        const int* __restrict__ sa1, const int* __restrict__ da1,
        const int* __restrict__ st1, int* __restrict__ cu1, int* __restrict__ cs1,
        const int* __restrict__ sa2, const int* __restrict__ da2,
        const int* __restrict__ st2, int* __restrict__ cu2, int* __restrict__ cs2) {
    int i = fb * 256 + threadIdx.x;
    const int *sa, *da, *st;
    int *cu, *cs;
    int Nd, Ns, e;
    if (i < E1) { sa = sa1; da = da1; st = st1; cu = cu1; cs = cs1; Nd = N2; Ns = N1; e = i; }
    else if (i < E1 + E2) { sa = sa2; da = da2; st = st2; cu = cu2; cs = cs2; Nd = N3; Ns = N2; e = i - E1; }
    else return;
    int d = da[e];
    if ((unsigned)d >= (unsigned)Nd) return;
    int p = atomicAdd(&cu[d], 1);
    int idx = st[d] + p;
    if (idx >= st[d + 1]) return;
    int s = sa[e];
    if ((unsigned)s >= (unsigned)Ns) s = 0;
    cs[idx] = s;
}

// ---------- ed precompute cores (ride in GEMM launches) ----------
// ed1[d,h] = x[d,:256] . v1dT[h,:]; one wave per node, fully coalesced row load.
__device__ __forceinline__ void ed1_core(const float* __restrict__ x, const float* __restrict__ v1dT,
                                         float* __restrict__ ed1, int blk) {
    const int lane = threadIdx.x & 63;
    const int w = threadIdx.x >> 6;
    float4 vv[8];
#pragma unroll
    for (int h = 0; h < 8; h++) vv[h] = *(const float4*)&v1dT[h * 256 + lane * 4];
    for (int i = 0; i < 4; i++) {
        int d = blk * 16 + w * 4 + i;
        if (d >= N2) return;
        float4 xv = *(const float4*)&x[(size_t)d * 256 + lane * 4];
        float p[8];
#pragma unroll
        for (int h = 0; h < 8; h++)
            p[h] = xv.x * vv[h].x + xv.y * vv[h].y + xv.z * vv[h].z + xv.w * vv[h].w;
#pragma unroll
        for (int off = 1; off < 64; off <<= 1)
#pragma unroll
            for (int h = 0; h < 8; h++) p[h] += __shfl_xor(p[h], off);
        if (lane < 8) {
            int hh = lane;
            float a01 = (hh & 1) ? p[1] : p[0], a23 = (hh & 1) ? p[3] : p[2];
            float a45 = (hh & 1) ? p[5] : p[4], a67 = (hh & 1) ? p[7] : p[6];
            float b0 = (hh & 2) ? a23 : a01, b1 = (hh & 2) ? a67 : a45;
            ed1[d * 8 + hh] = (hh & 4) ? b1 : b0;
        }
    }
}
// ed2[d,h] = acc1h[d,:512](fp16) . v2dT[h,:]
__device__ __forceinline__ void ed2_core(const unsigned short* __restrict__ xh,
                                         const float* __restrict__ v2dT,
                                         float* __restrict__ ed2, int blk) {
    const int lane = threadIdx.x & 63;
    const int w = threadIdx.x >> 6;
    float vv[4][8];
#pragma unroll
    for (int h = 0; h < 4; h++)
#pragma unroll
        for (int j = 0; j < 8; j++) vv[h][j] = v2dT[h * 512 + lane * 8 + j];
    for (int i = 0; i < 4; i++) {
        int d = blk * 16 + w * 4 + i;
        if (d >= N3) return;
        uint4v rw = *(const uint4v*)&xh[(size_t)d * 512 + lane * 8];
        const unsigned short* rb = (const unsigned short*)&rw;
        float xf[8];
#pragma unroll
        for (int j = 0; j < 8; j++) xf[j] = hu2f(rb[j]);
        float p[4];
#pragma unroll
        for (int h = 0; h < 4; h++) {
            float s = 0.f;
#pragma unroll
            for (int j = 0; j < 8; j++) s += xf[j] * vv[h][j];
            p[h] = s;
        }
#pragma unroll
        for (int off = 1; off < 64; off <<= 1)
#pragma unroll
            for (int h = 0; h < 4; h++) p[h] += __shfl_xor(p[h], off);
        if (lane < 4) {
            int hh = lane;
            float a01 = (hh & 1) ? p[1] : p[0], a23 = (hh & 1) ? p[3] : p[2];
            ed2[d * 4 + hh] = (hh & 2) ? a23 : a01;
        }
    }
}

// ---------- fp16 MFMA GEMM core, LDS-shared A, K-step 64; 2-deep A prefetch ----------
// C-store: direct per-element fp16 stores (round-11 proven epilogue).
template <bool AF16>
__device__ __forceinline__ void gemm_core(_Float16 (*As)[64][72],
              const void* __restrict__ Ax,
              const unsigned short* __restrict__ Bp, unsigned short* __restrict__ C,
              const float* __restrict__ att, float* __restrict__ es_out,
              int MT, int NB, int N, int K, int H, int hb) {
    const int xcd = hb & 7;
    const int sI = hb >> 3;
    const int mt = (sI / NB) * 8 + xcd;
    const int nb = sI % NB;
    if (mt >= MT) return;
    const int m0 = mt * 64;
    const int tid = threadIdx.x;
    const int wave = tid >> 6, lane = tid & 63;
    const int q = lane >> 4, l15 = lane & 15;
    const int n0 = nb * 256 + wave * 64;
    const int KS = K >> 6;
    const int KSB = K >> 5;
    const int arow = tid >> 2, ac16 = (tid & 3) * 16;
    const unsigned short* Bbase = Bp + (size_t)(n0 >> 4) * KSB * 512 + lane * 8;

    f32x4 acc[4][4] = {};
    half8 b[2][4];
    // staging reg sets (only the relevant dtype's set is live)
    float4 sA0, sA1, sA2, sA3, sB0, sB1, sB2, sB3;
    half8 hA0, hA1, hB0, hB1;

    auto loadS = [&](int t, int which) {   // which: 0 -> set A, 1 -> set B (literal)
        if constexpr (AF16) {
            const _Float16* p = (const _Float16*)Ax + (size_t)(m0 + arow) * K + t * 64 + ac16;
            if (which == 0) { hA0 = *(const half8*)p; hA1 = *(const half8*)(p + 8); }
            else            { hB0 = *(const half8*)p; hB1 = *(const half8*)(p + 8); }
        } else {
            const float* p = (const float*)Ax + (size_t)(m0 + arow) * K + t * 64 + ac16;
            if (which == 0) {
                sA0 = *(const float4*)p;       sA1 = *(const float4*)(p + 4);
                sA2 = *(const float4*)(p + 8); sA3 = *(const float4*)(p + 12);
            } else {
                sB0 = *(const float4*)p;       sB1 = *(const float4*)(p + 4);
                sB2 = *(const float4*)(p + 8); sB3 = *(const float4*)(p + 12);
            }
        }
    };
    auto writeS = [&](int buf, int which) {
        half8 v0, v1;
        if constexpr (AF16) {
            if (which == 0) { v0 = hA0; v1 = hA1; } else { v0 = hB0; v1 = hB1; }
        } else {
            float4 t0, t1, t2, t3;
            if (which == 0) { t0 = sA0; t1 = sA1; t2 = sA2; t3 = sA3; }
            else            { t0 = sB0; t1 = sB1; t2 = sB2; t3 = sB3; }
            v0[0] = (_Float16)t0.x; v0[1] = (_Float16)t0.y;
            v0[2] = (_Float16)t0.z; v0[3] = (_Float16)t0.w;
            v0[4] = (_Float16)t1.x; v0[5] = (_Float16)t1.y;
            v0[6] = (_Float16)t1.z; v0[7] = (_Float16)t1.w;
            v1[0] = (_Float16)t2.x; v1[1] = (_Float16)t2.y;
            v1[2] = (_Float16)t2.z; v1[3] = (_Float16)t2.w;
            v1[4] = (_Float16)t3.x; v1[5] = (_Float16)t3.y;
            v1[6] = (_Float16)t3.z; v1[7] = (_Float16)t3.w;
        }
        *(half8*)&As[buf][arow][ac16] = v0;
        *(half8*)&As[buf][arow][ac16 + 8] = v1;
    };
    auto loadB = [&](int k32, int kh, int nt) {
        b[kh][nt] = *(const half8*)(Bbase + ((size_t)nt * KSB + k32) * 512);
    };
    auto mstep = [&](int bufi, int tn) {   // MFMAs on buf; reload B for step tn (if >=0)
#pragma unroll
        for (int kh = 0; kh < 2; kh++)
#pragma unroll
            for (int rg = 0; rg < 4; rg++) {
                half8 a = *(const half8*)&As[bufi][rg * 16 + l15][kh * 32 + q * 8];
#pragma unroll
                for (int nt = 0; nt < 4; nt++) {
                    acc[rg][nt] = __builtin_amdgcn_mfma_f32_16x16x32_f16(a, b[kh][nt], acc[rg][nt], 0, 0, 0);
                    if (rg == 3 && tn >= 0) loadB(2 * tn + kh, kh, nt);
                }
            }
    };

    // prologue: A0 and A1 in flight; B0 frags; write A0; sync
    loadS(0, 0);
    if (KS > 1) loadS(1, 1);
#pragma unroll
    for (int kh = 0; kh < 2; kh++)
#pragma unroll
        for (int nt = 0; nt < 4; nt++) loadB(kh, kh, nt);
    writeS(0, 0);
    __syncthreads();

    // KS is even (4 or 8): even steps read buf0, odd steps read buf1
    for (int t = 0; t < KS; t += 2) {
        if (t + 2 < KS) loadS(t + 2, 0);          // issue A(t+2): 2 phases of cover
        mstep(0, (t + 1 < KS) ? t + 1 : -1);
        if (t + 1 < KS) {
            writeS(1, 1);                          // A(t+1) from set B -> buf1
            __syncthreads();
            if (t + 3 < KS) loadS(t + 3, 1);       // issue A(t+3)
            mstep(1, (t + 2 < KS) ? t + 2 : -1);
            if (t + 2 < KS) {
                writeS(0, 0);                      // A(t+2) from set A -> buf0
                __syncthreads();
            }
        }
    }

    // epilogue: C store (fp16, direct)
#pragma unroll
    for (int rg = 0; rg < 4; rg++)
#pragma unroll
        for (int nt = 0; nt < 4; nt++)
#pragma unroll
            for (int r = 0; r < 4; r++) {
                int row = m0 + rg * 16 + q * 4 + r;
                int col = n0 + nt * 16 + l15;
                C[(size_t)row * N + col] = f2hu(acc[rg][nt][r]);
            }
    // fused escore
    {
        const int head = n0 >> 6;
        float av[4];
#pragma unroll
        for (int nt = 0; nt < 4; nt++) av[nt] = att[head * 64 + nt * 16 + l15];
#pragma unroll
        for (int rg = 0; rg < 4; rg++)
#pragma unroll
            for (int r = 0; r < 4; r++) {
                float p = acc[rg][0][r] * av[0] + acc[rg][1][r] * av[1]
                        + acc[rg][2][r] * av[2] + acc[rg][3][r] * av[3];
#pragma unroll
                for (int off = 1; off < 16; off <<= 1) p += __shfl_xor(p, off);
                if (l15 == 0)
                    es_out[(size_t)(m0 + rg * 16 + q * 4 + r) * H + head] = p;
            }
    }
}

// ---------- layer-1 launch: fill + ed1 FIRST (overlap with gemm bulk), then GEMM ----------
__global__ __launch_bounds__(256, 2)
void gemm1_fused(const void* __restrict__ Ax,
                 const unsigned short* __restrict__ Bp, unsigned short* __restrict__ C,
                 const float* __restrict__ att, float* __restrict__ es_out,
                 int MT, int NB, int N, int K, int H, int FB, int EB,
                 const int* sa1, const int* da1, const int* st1, int* cu1, int* cs1,
                 const int* sa2, const int* da2, const int* st2, int* cu2, int* cs2,
                 const float* __restrict__ xe, const float* __restrict__ v1dT,
                 float* __restrict__ ed1) {
    __shared__ alignas(16) _Float16 As[2][64][72];
    const int bid = blockIdx.x;
    if (bid < FB) fill_core(bid, sa1, da1, st1, cu1, cs1, sa2, da2, st2, cu2, cs2);
    else if (bid < FB + EB) ed1_core(xe, v1dT, ed1, bid - FB);
    else gemm_core<false>(As, Ax, Bp, C, att, es_out, MT, NB, N, K, H, bid - FB - EB);
}

// ---------- flat MLP core (64x64 tile, Bt3 bf16 hi/lo, fp32 A in-kernel split) ----------
__device__ __forceinline__ void flat_core(unsigned char* smemraw,
        const float* __restrict__ A, const unsigned short* __restrict__ Bt3,
        float* __restrict__ C, int mb) {
    const int K = 128, N = 64, KK = 384;
    auto As = (unsigned short (*)[64][72])smemraw;
    auto Bs = (unsigned short (*)[72])(smemraw + 18432);
    const int tid = threadIdx.x;
    const int wave = tid >> 6, lane = tid & 63;
    const int wr = wave >> 1, wc = wave & 1;
    const int quad = lane >> 4, l15 = lane & 15;
    const int m0 = mb * 64, n0 = 0;
    f32x4 acc[2][2] = {};
    for (int k0 = 0; k0 < KK; k0 += 64) {
        const int seg = k0 / K;
        const int ks = k0 - seg * K;
#pragma unroll
        for (int i = 0; i < 2; i++) {
            int idx = tid + i * 256;
            int r = idx >> 3, cv = (idx & 7) * 8;
            const float* ap = &A[(size_t)(m0 + r) * K + ks + cv];
            const float4 v0 = *(const float4*)ap;
            const float4 v1 = *(const float4*)(ap + 4);
            float va[8] = {v0.x, v0.y, v0.z, v0.w, v1.x, v1.y, v1.z, v1.w};
            short8 h8, l8;
#pragma unroll
            for (int j = 0; j < 8; j++) {
                unsigned short hh = f2bfu(va[j]);
                h8[j] = (short)hh;
                l8[j] = (short)f2bfu(va[j] - bfu2f(hh));
            }
            *(short8*)&As[0][r][cv] = h8;
            *(short8*)&As[1][r][cv] = l8;
            *(short8*)&Bs[r][cv] = *(const short8*)&Bt3[(size_t)(n0 + r) * KK + k0 + cv];
        }
        __syncthreads();
        const int abank = (seg < 2) ? 0 : 1;
#pragma unroll
        for (int kk = 0; kk < 64; kk += 32) {
            short8 a[2], b[2];
#pragma unroll
            for (int t = 0; t < 2; t++) {
                a[t] = *(const short8*)&As[abank][wr * 32 + t * 16 + l15][kk + quad * 8];
                b[t] = *(const short8*)&Bs[wc * 32 + t * 16 + l15][kk + quad * 8];
            }
#pragma unroll
            for (int mt = 0; mt < 2; mt++)
#pragma unroll
                for (int nt = 0; nt < 2; nt++)
                    acc[mt][nt] = __builtin_amdgcn_mfma_f32_16x16x32_bf16(
                        a[mt], b[nt], acc[mt][nt], 0, 0, 0);
        }
        __syncthreads();
    }
#pragma unroll
    for (int mt = 0; mt < 2; mt++)
#pragma unroll
        for (int nt = 0; nt < 2; nt++)
#pragma unroll
            for (int r = 0; r < 4; r++) {
                int row = m0 + wr * 32 + mt * 16 + quad * 4 + r;
                int col = n0 + wc * 32 + nt * 16 + l15;
                C[(size_t)row * N + col] = acc[mt][nt][r];
            }
}

// ---------- layer-2 launch: flat + ed2 first, then GEMM ----------
__global__ __launch_bounds__(256, 2)
void gemm2_fused(const void* __restrict__ Ax,
                 const unsigned short* __restrict__ Bp, unsigned short* __restrict__ C,
                 const float* __restrict__ att, float* __restrict__ es_out,
                 int MT, int NB, int N, int K, int H, int FLB, int EB2,
                 const float* __restrict__ fA, const unsigned short* __restrict__ fBt3,
                 float* __restrict__ fC,
                 const unsigned short* __restrict__ x2h, const float* __restrict__ v2dT,
                 float* __restrict__ ed2) {
    __shared__ alignas(16) unsigned char smem[27648];
    const int bid = blockIdx.x;
    if (bid < FLB) flat_core(smem, fA, fBt3, fC, bid);
    else if (bid < FLB + EB2) ed2_core(x2h, v2dT, ed2, bid - FLB);
    else gemm_core<true>((_Float16(*)[64][72])smem, Ax, Bp, C, att, es_out,
                         MT, NB, N, K, H, bid - FLB - EB2);
}

// ---------- GAT aggregate v3: csr-once + shfl distribution + fp16 dot2 gather ----------
// One wave per dst node. edh from precomputed edv (1 load). Neighbor list loaded once
// coalesced into regs (fast path n<=64 for H=8, n<=128 for H=4); alpha es loads batched;
// gather chunks software-pipelined with double reg-buffers; rows fp16, inner loop
// v_perm + v_dot2_f32_f16 (2 rows per op). FIN: fused output head.
template <int H, bool ELU, bool HOUT, bool FIN>
__global__ __launch_bounds__(256)
void gat_agg3(const int* __restrict__ csr, const int* __restrict__ rs,
              const unsigned short* __restrict__ hs,  // [Ns, H*64] fp16
              const float* __restrict__ es,           // [Ns, H]
              const float* __restrict__ edv,          // [Nd, H]
              const float* __restrict__ bias,
              void* __restrict__ out, int Nd,
              const float* __restrict__ fbuf, const float* __restrict__ flat_b,
              const float* __restrict__ last, const float* __restrict__ outW,
              const float* __restrict__ outb, float* __restrict__ fout) {
    constexpr int LH = (H == 8) ? 3 : 2;
    constexpr int EPC = 64 >> LH;          // rows per chunk: 8 (H=8) / 16 (H=4)
    constexpr int ND = H / 2;              // dwords per lane row-slice
    const int lane = threadIdx.x & 63;
    const int d = blockIdx.x * 4 + (threadIdx.x >> 6);
    if (d >= Nd) return;
    const int h = lane & (H - 1);
    const int e0 = lane >> LH;
    const int hB = lane >> (6 - LH);
    const float edh = edv[(size_t)d * H + h];
    const int beg = rs[d];
    const int deg = rs[d + 1] - beg;
    const int n = deg + 1;
    const int nch = (n + EPC - 1) / EPC;
    float acc[H] = {};
    const size_t rowoff = (size_t)lane * H;
    if (nch <= 8) {
        // --- neighbor indices: ONE coalesced load per wave ---
        int idxA = d, idxB = d;
        if (lane < deg) idxA = csr[beg + lane];
        if constexpr (H == 4) { if (64 + lane < deg) idxB = csr[beg + 64 + lane]; }
        // --- batched es loads (1 round trip) ---
        float av[8];
#pragma unroll
        for (int c = 0; c < 8; c++) {
            if (c < nch) {
                int jv = c * EPC + e0;
                int s;
                if (c * EPC + EPC - 1 < 64) s = __shfl(idxA, jv);
                else s = __shfl(idxB, jv - 64);
                av[c] = es[(size_t)s * H + h];
            }
        }
        // --- chunk row loads (pipelined, double reg buffer) ---
        unsigned rvA[EPC][ND], rvB[EPC][ND];
        auto loadChunk = [&](int c, unsigned (&rv)[EPC][ND]) {
#pragma unroll
            for (int u = 0; u < EPC; u++) {
                int src = c * EPC + u;
                int s = (src < 64) ? __shfl(idxA, src) : __shfl(idxB, src - 64);
                const unsigned short* rp = &hs[(size_t)s * (H * 64) + rowoff];
                if constexpr (H == 8) *(uint4v*)&rv[u][0] = *(const uint4v*)rp;
                else *(uint2v*)&rv[u][0] = *(const uint2v*)rp;
            }
        };
        loadChunk(0, rvA);   // overlaps softmax below
        // --- softmax from cached alphas ---
        float al[8], mx = -1e30f;
#pragma unroll
        for (int c = 0; c < 8; c++) {
            int jv = c * EPC + e0;
            float a = -1e30f;
            if (c < nch && jv < n) { a = av[c] + edh; a = (a > 0.f) ? a : 0.2f * a; }
            al[c] = a;
            mx = fmaxf(mx, a);
        }
#pragma unroll
        for (int off = H; off < 64; off <<= 1) mx = fmaxf(mx, __shfl_xor(mx, off));
        float exv[8], den = 0.f;
#pragma unroll
        for (int c = 0; c < 8; c++) { exv[c] = expf(al[c] - mx); den += exv[c]; }
#pragma unroll
        for (int off = H; off < 64; off <<= 1) den += __shfl_xor(den, off);
        const float inv = 1.f / den;
        float ec[8];
#pragma unroll
        for (int c = 0; c < 8; c++) ec[c] = exv[c] * inv;
        // --- gather: guard-free, paired-row dot2 ---
        auto computeChunk = [&](int c, unsigned (&rv)[EPC][ND]) {
#pragma unroll
            for (int pu = 0; pu < EPC / 2; pu++) {
                float w0 = __shfl(ec[c], (2 * pu) * H + hB);
                float w1 = __shfl(ec[c], (2 * pu + 1) * H + hB);
#ifdef USE_DOT2
                unsigned w2 = pkw(w0, w1);
#pragma unroll
                for (int dwi = 0; dwi < ND; dwi++) {
                    unsigned lo = __builtin_amdgcn_perm(rv[2 * pu + 1][dwi], rv[2 * pu][dwi], 0x05040100u);
                    unsigned hi = __builtin_amdgcn_perm(rv[2 * pu + 1][dwi], rv[2 * pu][dwi], 0x07060302u);
                    acc[2 * dwi] = fdot2acc(w2, lo, acc[2 * dwi]);
                    acc[2 * dwi + 1] = fdot2acc(w2, hi, acc[2 * dwi + 1]);
                }
#else
#pragma unroll
                for (int dwi = 0; dwi < ND; dwi++) {
                    unsigned q0 = rv[2 * pu][dwi], q1 = rv[2 * pu + 1][dwi];
                    acc[2 * dwi]     += w0 * hu2f((unsigned short)(q0 & 0xffff))
                                      + w1 * hu2f((unsigned short)(q1 & 0xffff));
                    acc[2 * dwi + 1] += w0 * hu2f((unsigned short)(q0 >> 16))
                                      + w1 * hu2f((unsigned short)(q1 >> 16));
                }
#endif
            }
        };
#pragma unroll
        for (int c = 0; c < 8; c += 2) {
            if (c >= nch) break;
            if (c + 1 < nch) loadChunk(c + 1, rvB);
            computeChunk(c, rvA);
            if (c + 1 >= nch) break;
            if (c + 2 < nch) loadChunk(c + 2, rvA);
            computeChunk(c + 1, rvB);
        }
    } else {
        // fallback two-pass (very rare large-degree nodes)
        float mx = -1e30f;
        for (int j0 = 0; j0 < n; j0 += EPC) {
            int j = j0 + e0;
            if (j < n) {
                int s = (j < deg) ? csr[beg + j] : d;
                float a = es[(size_t)s * H + h] + edh;
                a = (a > 0.0f) ? a : 0.2f * a;
                mx = fmaxf(mx, a);
            }
        }
#pragma unroll
        for (int off = H; off < 64; off <<= 1) mx = fmaxf(mx, __shfl_xor(mx, off));
        float den = 0.0f;
        for (int j0 = 0; j0 < n; j0 += EPC) {
            int j = j0 + e0;
            if (j < n) {
                int s = (j < deg) ? csr[beg + j] : d;
                float a = es[(size_t)s * H + h] + edh;
                a = (a > 0.0f) ? a : 0.2f * a;
                den += expf(a - mx);
            }
        }
#pragma unroll
        for (int off = H; off < 64; off <<= 1) den += __shfl_xor(den, off);
        const float inv = 1.0f / den;
        const float mB = __shfl(mx, hB);
        const float invB = __shfl(inv, hB);
        const float edhB = __shfl(edh, hB);
        for (int j = 0; j < n; j++) {
            int s = (j < deg) ? csr[beg + j] : d;
            const unsigned short* rp = &hs[(size_t)s * (H * 64) + rowoff];
            float a = es[(size_t)s * H + hB] + edhB;
            a = (a > 0.0f) ? a : 0.2f * a;
            float w = expf(a - mB) * invB;
#pragma unroll
            for (int k = 0; k < H; k++) acc[k] += w * hu2f(rp[k]);
        }
    }
    if constexpr (FIN) {
        float f4[4];
#pragma unroll
        for (int k = 0; k < 4; k++) {
            float a2v = acc[k] + __shfl_xor(acc[k], 32);
            f4[k] = a2v + __shfl_xor(a2v, 16);
        }
        float part = 0.f;
        if (lane < 16) {
            const int c0 = lane * 4;
            float4 fb4 = *(const float4*)&fbuf[(size_t)d * 64 + c0];
            float4 lb4 = *(const float4*)&last[(size_t)d * 64 + c0];
            const float* fbv = &fb4.x;
            const float* lbv = &lb4.x;
#pragma unroll
            for (int k = 0; k < 4; k++) {
                int c = c0 + k;
                float h2 = 0.25f * f4[k] + bias[c];
                part += h2 * outW[c];
                part += (fbv[k] + flat_b[c]) * outW[64 + c];
                part += lbv[k] * outW[128 + c];
            }
        }
#pragma unroll
        for (int off = 1; off < 16; off <<= 1) part += __shfl_xor(part, off);
        if (lane == 0) fout[d] = part + outb[0];
    } else {
#pragma unroll
        for (int k = 0; k < H; k++) {
            float v = acc[k];
            if (ELU) {
                v += bias[lane * H + k];
                v = (v > 0.0f) ? v : expm1f(v);
            }
            acc[k] = v;
        }
        if constexpr (HOUT) {
            half8 hv;
#pragma unroll
            for (int k = 0; k < H; k++) hv[k] = (_Float16)acc[k];
            _Float16* op = (_Float16*)out + (size_t)d * (H * 64) + rowoff;
            *(half8*)op = hv;
        } else {
            float* op = (float*)out + (size_t)d * (H * 64) + rowoff;
#pragma unroll
            for (int qd = 0; qd < H / 4; qd++)
                *(float4*)&op[qd * 4] = *(float4*)&acc[qd * 4];
        }
    }
}

extern "C" void kernel_launch(void* const* d_in, const int* in_sizes, int n_in,
                              void* d_out, int out_size, void* d_ws, size_t ws_size,
                              hipStream_t stream) {
    const float* x    = (const float*)d_in[0];
    const float* flat = (const float*)d_in[1];
    const float* last = (const float*)d_in[2];
    const int*  es1i  = (const int*)d_in[3];
    const int*  ed1i  = (const int*)d_in[4];
    const int*  es2i  = (const int*)d_in[5];
    const int*  ed2i  = (const int*)d_in[6];
    const float* W1s  = (const float*)d_in[7];
    const float* W1d  = (const float*)d_in[8];
    const float* a1s  = (const float*)d_in[9];
    const float* a1d  = (const float*)d_in[10];
    const float* b1   = (const float*)d_in[11];
    const float* W2s  = (const float*)d_in[12];
    const float* W2d  = (const float*)d_in[13];
    const float* a2s  = (const float*)d_in[14];
    const float* a2d  = (const float*)d_in[15];
    const float* b2   = (const float*)d_in[16];
    const float* fW   = (const float*)d_in[17];
    const float* fb   = (const float*)d_in[18];
    const float* oW   = (const float*)d_in[19];
    const float* ob   = (const float*)d_in[20];
    float* out = (float*)d_out;

    float* ws = (float*)d_ws;
    // ---- layout (float-element offsets; proven footprint) ----
    unsigned short* hs1_h = (unsigned short*)ws;                   // [80000][512] fp16
    float* es1f = ws + 24576000;                                   // [80000][8]
    float* ed1f = ws + 25216000;                                   // [16000][8]
    float* acc1 = ws + 25344000;                                   // L1 out, fp16 [16000][512]
    unsigned short* wb = (unsigned short*)(ws + 54016000);
    unsigned short* w1s_pk = wb;                                   // 131072 us
    unsigned short* w2s_pk = wb + 524288;                          // 131072 us
    unsigned short* fw_t3  = wb + 1048576;                         // 24576 us
    float* v1dT = ws + 54600000;                                   // 2048
    float* v2dT = ws + 54602048;                                   // 2048
    int* ibase   = (int*)(ws + 54816000);
    int* cnt1    = ibase;
    int* cursor1 = ibase + 16000;
    int* cnt2    = ibase + 32000;
    int* cursor2 = ibase + 36096;
    int* start1  = ibase + 40192;
    int* start2  = ibase + 56193;
    int* csr1    = ibase + 60290;
    int* csr2    = ibase + 316290;
    const size_t NEED = ((size_t)54816000 + 381826) * 4;
    if (ws_size < NEED) {
        fprintf(stderr, "kernel_launch: ws_size %zu < needed %zu\n", ws_size, NEED);
        return;
    }
    unsigned short* hs2_h = (unsigned short*)ws;                   // [16000][256] fp16
    float* es2f = ws + 2572288;
    float* ed2f = ws + 2636288;                                    // [4096][4]
    float* fbuf = ws + 3701248;
    unsigned short* acc1h = (unsigned short*)acc1;

    // ---- zero counters/cursors, then prep+hist (1 launch) + scan ----
    (void)hipMemsetAsync(ibase, 0, 40192 * sizeof(int), stream);
    {
        const int PB = 1072;   // (131072+131072+8192+4096)/256
        const int HB = (E1 + E2) / 256;   // 1256
        prep_hist<<<PB + HB, 256, 0, stream>>>(
            W1s, w1s_pk, W2s, w2s_pk,
            W1d, a1d, v1dT, W2d, a2d, v2dT,
            fW, fw_t3, PB, ed1i, cnt1, ed2i, cnt2);
    }
    scan_dual<<<2, 1024, 0, stream>>>(cnt1, start1, N2, cnt2, start2, N3);

    // ---- layer 1: fill + ed1 riders first, then GEMM bulk (one launch) ----
    {
        const int MT = N1 / 64;             // 1250
        const int NB = 2;
        const int G1 = 8 * NB * ((MT + 7) / 8);   // 2512
        const int FB = (E1 + E2) / 256;           // 1256
        const int EB = N2 / 16;                   // 1000
        gemm1_fused<<<FB + EB + G1, 256, 0, stream>>>(
            x, w1s_pk, hs1_h, a1s, es1f, MT, NB, 512, 256, 8, FB, EB,
            es1i, ed1i, start1, cursor1, csr1, es2i, ed2i, start2, cursor2, csr2,
            x, v1dT, ed1f);
    }
    gat_agg3<8, true, true, false><<<N2 / 4, 256, 0, stream>>>(
        csr1, start1, hs1_h, es1f, ed1f, b1, acc1h, N2,
        nullptr, nullptr, nullptr, nullptr, nullptr, nullptr);

    // ---- layer 2: flat + ed2 riders first, then GEMM (one launch) ----
    {
        const int MT = N2 / 64;             // 250
        const int G2 = 8 * ((MT + 7) / 8);  // 256
        const int FLB = N3 / 64;            // 64
        const int EB2 = N3 / 16;            // 256
        gemm2_fused<<<FLB + EB2 + G2, 256, 0, stream>>>(
            acc1h, w2s_pk, hs2_h, a2s, es2f, MT, 1, 256, 512, 4, FLB, EB2,
            flat, fw_t3, fbuf,
            acc1h, v2dT, ed2f);
    }
    // ---- fused agg2 + output head ----
    gat_agg3<4, false, false, true><<<N3 / 4, 256, 0, stream>>>(
        csr2, start2, hs2_h, es2f, ed2f, b2, nullptr, N3,
        fbuf, fb, last, oW, ob, out);
}

// Round 14
// 318.603 us; speedup vs baseline: 1.0444x; 1.0315x over previous
//
#include <hip/hip_runtime.h>
#include <hip/hip_bf16.h>
#include <cstdio>

typedef __attribute__((ext_vector_type(8))) short short8;
typedef __attribute__((ext_vector_type(8))) _Float16 half8;
typedef __attribute__((ext_vector_type(2))) __fp16 fp16x2;
typedef __attribute__((ext_vector_type(4))) float f32x4;
typedef __attribute__((ext_vector_type(4))) unsigned int uint4v;
typedef __attribute__((ext_vector_type(2))) unsigned int uint2v;

#if defined(__has_builtin)
#if __has_builtin(__builtin_amdgcn_fdot2) && __has_builtin(__builtin_amdgcn_perm) && __has_builtin(__builtin_amdgcn_cvt_pkrtz)
#define USE_DOT2 1
#endif
#endif

// ---------- bf16/fp16 helpers ----------
__device__ __forceinline__ float bfu2f(unsigned short u) {
    return __uint_as_float(((unsigned)u) << 16);
}
__device__ __forceinline__ unsigned short f2bfu(float f) {   // RNE
    __hip_bfloat16 b = __float2bfloat16(f);
    union { __hip_bfloat16 b; unsigned short u; } cv; cv.b = b;
    return cv.u;
}
__device__ __forceinline__ unsigned short f2hu(float f) {    // fp16 RNE bits
    _Float16 h = (_Float16)f;
    union { _Float16 h; unsigned short u; } cv; cv.h = h;
    return cv.u;
}
__device__ __forceinline__ float hu2f(unsigned short u) {
    union { unsigned short u; _Float16 h; } cv; cv.u = u;
    return (float)cv.h;
}
#ifdef USE_DOT2
__device__ __forceinline__ unsigned pkw(float w0, float w1) {
    union { fp16x2 v; unsigned u; } cv;
    cv.v = __builtin_amdgcn_cvt_pkrtz(w0, w1);
    return cv.u;
}
__device__ __forceinline__ float fdot2acc(unsigned a, unsigned b, float c) {
    union { unsigned u; fp16x2 v; } ua, ub; ua.u = a; ub.u = b;
    return __builtin_amdgcn_fdot2(ua.v, ub.v, c, false);
}
#endif

// ---------- graph/model dims ----------
#define N1 80000
#define N2 16000
#define N3 4096
#define E1 256000
#define E2 65536

// ---------- prep + hist (one launch; int zeroing via hipMemsetAsync) ----------
__global__ void prep_hist(const float* __restrict__ W1s, unsigned short* __restrict__ w1s_pk,
                          const float* __restrict__ W2s, unsigned short* __restrict__ w2s_pk,
                          const float* __restrict__ W1d, const float* __restrict__ a1d,
                          float* __restrict__ v1dT,
                          const float* __restrict__ W2d, const float* __restrict__ a2d,
                          float* __restrict__ v2dT,
                          const float* __restrict__ fW, unsigned short* __restrict__ fw_t3,
                          int PB,
                          const int* __restrict__ ed1i, int* __restrict__ cnt1,
                          const int* __restrict__ ed2i, int* __restrict__ cnt2) {
    const int bid = blockIdx.x;
    if (bid < PB) {
        int i = bid * 256 + threadIdx.x;
        const int S0 = 131072, S1 = 131072, S2 = 8192;
        if (i < S0) {
            int k = i >> 9, n = i & 511;            // [K=256][N=512] row-major, KSB=8
            int n16 = n >> 4, l = n & 15, k32 = k >> 5, qq = (k >> 3) & 3, e = k & 7;
            size_t base = ((size_t)(n16 * 8 + k32)) * 512 + (qq * 16 + l) * 8 + e;
            w1s_pk[base] = f2hu(W1s[i]);
        } else if (i < S0 + S1) {
            int j = i - S0;
            int k = j >> 8, n = j & 255;            // [K=512][N=256] row-major, KSB=16
            int n16 = n >> 4, l = n & 15, k32 = k >> 5, qq = (k >> 3) & 3, e = k & 7;
            size_t base = ((size_t)(n16 * 16 + k32)) * 512 + (qq * 16 + l) * 8 + e;
            w2s_pk[base] = f2hu(W2s[j]);
        } else if (i < S0 + S1 + S2) {
            int j = i - S0 - S1;
            int k = j >> 6, n = j & 63;             // K=128, N=64 (flat MLP, bf16 hi/lo)
            float v = fW[j];
            unsigned short h = f2bfu(v);
            unsigned short l = f2bfu(v - bfu2f(h));
            size_t base = (size_t)n * 384;
            fw_t3[base + k] = h;
            fw_t3[base + 128 + k] = l;
            fw_t3[base + 256 + k] = h;
        } else {
            int j = i - S0 - S1 - S2;
            if (j < 2048) {                          // v1dT [8][256]
                int h = j >> 8, k = j & 255;
                float s = 0.f;
                for (int c = 0; c < 64; c++) s += W1d[k * 512 + h * 64 + c] * a1d[h * 64 + c];
                v1dT[j] = s;
            } else if (j < 4096) {                   // v2dT [4][512]
                int jj = j - 2048;
                int h = jj >> 9, k = jj & 511;
                float s = 0.f;
                for (int c = 0; c < 64; c++) s += W2d[k * 256 + h * 64 + c] * a2d[h * 64 + c];
                v2dT[jj] = s;
            }
        }
    } else {
        int i = (bid - PB) * 256 + threadIdx.x;
        if (i < E1) {
            int d = ed1i[i];
            if ((unsigned)d < (unsigned)N2) atomicAdd(&cnt1[d], 1);
        } else if (i < E1 + E2) {
            int d = ed2i[i - E1];
            if ((unsigned)d < (unsigned)N3) atomicAdd(&cnt2[d], 1);
        }
    }
}

__global__ __launch_bounds__(1024)
void scan_dual(const int* __restrict__ c1, int* __restrict__ s1, int Nd1,
               const int* __restrict__ c2, int* __restrict__ s2, int Nd2) {
    const int* cnt = (blockIdx.x == 0) ? c1 : c2;
    int* start = (blockIdx.x == 0) ? s1 : s2;
    int Nd = (blockIdx.x == 0) ? Nd1 : Nd2;
    __shared__ int part[1024];
    int t = threadIdx.x;
    int k = (Nd + 1023) >> 10;
    int lo = t * k, hi = min(lo + k, Nd);
    if (lo > Nd) lo = Nd;
    int s = 0;
    for (int i = lo; i < hi; i++) s += cnt[i];
    part[t] = s;
    __syncthreads();
    for (int off = 1; off < 1024; off <<= 1) {
        int v = (t >= off) ? part[t - off] : 0;
        __syncthreads();
        part[t] += v;
        __syncthreads();
    }
    int run = (t > 0) ? part[t - 1] : 0;
    for (int i = lo; i < hi; i++) { start[i] = run; run += cnt[i]; }
    if (t == 1023) start[Nd] = part[1023];
}

__device__ __forceinline__ void fill_core(int fb,
        const int* __restrict__ sa1, const int* __restrict__ da1,
        const int* __restrict__ st1, int* __restrict__ cu1, int* __restrict__ cs1,
        const int* __restrict__ sa2, const int* __restrict__ da2,
        const int* __restrict__ st2, int* __restrict__ cu2, int* __restrict__ cs2) {
    int i = fb * 256 + threadIdx.x;
    const int *sa, *da, *st;
    int *cu, *cs;
    int Nd, Ns, e;
    if (i < E1) { sa = sa1; da = da1; st = st1; cu = cu1; cs = cs1; Nd = N2; Ns = N1; e = i; }
    else if (i < E1 + E2) { sa = sa2; da = da2; st = st2; cu = cu2; cs = cs2; Nd = N3; Ns = N2; e = i - E1; }
    else return;
    int d = da[e];
    if ((unsigned)d >= (unsigned)Nd) return;
    int p = atomicAdd(&cu[d], 1);
    int idx = st[d] + p;
    if (idx >= st[d + 1]) return;
    int s = sa[e];
    if ((unsigned)s >= (unsigned)Ns) s = 0;
    cs[idx] = s;
}

// ---------- ed precompute cores (ride in GEMM launches) ----------
// ed1[d,h] = x[d,:256] . v1dT[h,:]; one wave per node, fully coalesced row load.
__device__ __forceinline__ void ed1_core(const float* __restrict__ x, const float* __restrict__ v1dT,
                                         float* __restrict__ ed1, int blk) {
    const int lane = threadIdx.x & 63;
    const int w = threadIdx.x >> 6;
    float4 vv[8];
#pragma unroll
    for (int h = 0; h < 8; h++) vv[h] = *(const float4*)&v1dT[h * 256 + lane * 4];
    for (int i = 0; i < 4; i++) {
        int d = blk * 16 + w * 4 + i;
        if (d >= N2) return;
        float4 xv = *(const float4*)&x[(size_t)d * 256 + lane * 4];
        float p[8];
#pragma unroll
        for (int h = 0; h < 8; h++)
            p[h] = xv.x * vv[h].x + xv.y * vv[h].y + xv.z * vv[h].z + xv.w * vv[h].w;
#pragma unroll
        for (int off = 1; off < 64; off <<= 1)
#pragma unroll
            for (int h = 0; h < 8; h++) p[h] += __shfl_xor(p[h], off);
        if (lane < 8) {
            int hh = lane;
            float a01 = (hh & 1) ? p[1] : p[0], a23 = (hh & 1) ? p[3] : p[2];
            float a45 = (hh & 1) ? p[5] : p[4], a67 = (hh & 1) ? p[7] : p[6];
            float b0 = (hh & 2) ? a23 : a01, b1 = (hh & 2) ? a67 : a45;
            ed1[d * 8 + hh] = (hh & 4) ? b1 : b0;
        }
    }
}
// ed2[d,h] = acc1h[d,:512](fp16) . v2dT[h,:]
__device__ __forceinline__ void ed2_core(const unsigned short* __restrict__ xh,
                                         const float* __restrict__ v2dT,
                                         float* __restrict__ ed2, int blk) {
    const int lane = threadIdx.x & 63;
    const int w = threadIdx.x >> 6;
    float vv[4][8];
#pragma unroll
    for (int h = 0; h < 4; h++)
#pragma unroll
        for (int j = 0; j < 8; j++) vv[h][j] = v2dT[h * 512 + lane * 8 + j];
    for (int i = 0; i < 4; i++) {
        int d = blk * 16 + w * 4 + i;
        if (d >= N3) return;
        uint4v rw = *(const uint4v*)&xh[(size_t)d * 512 + lane * 8];
        const unsigned short* rb = (const unsigned short*)&rw;
        float xf[8];
#pragma unroll
        for (int j = 0; j < 8; j++) xf[j] = hu2f(rb[j]);
        float p[4];
#pragma unroll
        for (int h = 0; h < 4; h++) {
            float s = 0.f;
#pragma unroll
            for (int j = 0; j < 8; j++) s += xf[j] * vv[h][j];
            p[h] = s;
        }
#pragma unroll
        for (int off = 1; off < 64; off <<= 1)
#pragma unroll
            for (int h = 0; h < 4; h++) p[h] += __shfl_xor(p[h], off);
        if (lane < 4) {
            int hh = lane;
            float a01 = (hh & 1) ? p[1] : p[0], a23 = (hh & 1) ? p[3] : p[2];
            ed2[d * 4 + hh] = (hh & 2) ? a23 : a01;
        }
    }
}

// ---------- fp16 MFMA GEMM core, LDS-shared A, K-step 64; 2-deep A prefetch ----------
// C-store: direct per-element fp16 stores.
template <bool AF16>
__device__ __forceinline__ void gemm_core(_Float16 (*As)[64][72],
              const void* __restrict__ Ax,
              const unsigned short* __restrict__ Bp, unsigned short* __restrict__ C,
              const float* __restrict__ att, float* __restrict__ es_out,
              int MT, int NB, int N, int K, int H, int hb) {
    const int xcd = hb & 7;
    const int sI = hb >> 3;
    const int mt = (sI / NB) * 8 + xcd;
    const int nb = sI % NB;
    if (mt >= MT) return;
    const int m0 = mt * 64;
    const int tid = threadIdx.x;
    const int wave = tid >> 6, lane = tid & 63;
    const int q = lane >> 4, l15 = lane & 15;
    const int n0 = nb * 256 + wave * 64;
    const int KS = K >> 6;
    const int KSB = K >> 5;
    const int arow = tid >> 2, ac16 = (tid & 3) * 16;
    const unsigned short* Bbase = Bp + (size_t)(n0 >> 4) * KSB * 512 + lane * 8;

    f32x4 acc[4][4] = {};
    half8 b[2][4];
    // staging reg sets (only the relevant dtype's set is live)
    float4 sA0, sA1, sA2, sA3, sB0, sB1, sB2, sB3;
    half8 hA0, hA1, hB0, hB1;

    auto loadS = [&](int t, int which) {   // which: 0 -> set A, 1 -> set B (literal)
        if constexpr (AF16) {
            const _Float16* p = (const _Float16*)Ax + (size_t)(m0 + arow) * K + t * 64 + ac16;
            if (which == 0) { hA0 = *(const half8*)p; hA1 = *(const half8*)(p + 8); }
            else            { hB0 = *(const half8*)p; hB1 = *(const half8*)(p + 8); }
        } else {
            const float* p = (const float*)Ax + (size_t)(m0 + arow) * K + t * 64 + ac16;
            if (which == 0) {
                sA0 = *(const float4*)p;       sA1 = *(const float4*)(p + 4);
                sA2 = *(const float4*)(p + 8); sA3 = *(const float4*)(p + 12);
            } else {
                sB0 = *(const float4*)p;       sB1 = *(const float4*)(p + 4);
                sB2 = *(const float4*)(p + 8); sB3 = *(const float4*)(p + 12);
            }
        }
    };
    auto writeS = [&](int buf, int which) {
        half8 v0, v1;
        if constexpr (AF16) {
            if (which == 0) { v0 = hA0; v1 = hA1; } else { v0 = hB0; v1 = hB1; }
        } else {
            float4 t0, t1, t2, t3;
            if (which == 0) { t0 = sA0; t1 = sA1; t2 = sA2; t3 = sA3; }
            else            { t0 = sB0; t1 = sB1; t2 = sB2; t3 = sB3; }
            v0[0] = (_Float16)t0.x; v0[1] = (_Float16)t0.y;
            v0[2] = (_Float16)t0.z; v0[3] = (_Float16)t0.w;
            v0[4] = (_Float16)t1.x; v0[5] = (_Float16)t1.y;
            v0[6] = (_Float16)t1.z; v0[7] = (_Float16)t1.w;
            v1[0] = (_Float16)t2.x; v1[1] = (_Float16)t2.y;
            v1[2] = (_Float16)t2.z; v1[3] = (_Float16)t2.w;
            v1[4] = (_Float16)t3.x; v1[5] = (_Float16)t3.y;
            v1[6] = (_Float16)t3.z; v1[7] = (_Float16)t3.w;
        }
        *(half8*)&As[buf][arow][ac16] = v0;
        *(half8*)&As[buf][arow][ac16 + 8] = v1;
    };
    auto loadB = [&](int k32, int kh, int nt) {
        b[kh][nt] = *(const half8*)(Bbase + ((size_t)nt * KSB + k32) * 512);
    };
    auto mstep = [&](int bufi, int tn) {   // MFMAs on buf; reload B for step tn (if >=0)
#pragma unroll
        for (int kh = 0; kh < 2; kh++)
#pragma unroll
            for (int rg = 0; rg < 4; rg++) {
                half8 a = *(const half8*)&As[bufi][rg * 16 + l15][kh * 32 + q * 8];
#pragma unroll
                for (int nt = 0; nt < 4; nt++) {
                    acc[rg][nt] = __builtin_amdgcn_mfma_f32_16x16x32_f16(a, b[kh][nt], acc[rg][nt], 0, 0, 0);
                    if (rg == 3 && tn >= 0) loadB(2 * tn + kh, kh, nt);
                }
            }
    };

    // prologue: A0 and A1 in flight; B0 frags; write A0; sync
    loadS(0, 0);
    if (KS > 1) loadS(1, 1);
#pragma unroll
    for (int kh = 0; kh < 2; kh++)
#pragma unroll
        for (int nt = 0; nt < 4; nt++) loadB(kh, kh, nt);
    writeS(0, 0);
    __syncthreads();

    // KS is even (4 or 8): even steps read buf0, odd steps read buf1
    for (int t = 0; t < KS; t += 2) {
        if (t + 2 < KS) loadS(t + 2, 0);          // issue A(t+2): 2 phases of cover
        mstep(0, (t + 1 < KS) ? t + 1 : -1);
        if (t + 1 < KS) {
            writeS(1, 1);                          // A(t+1) from set B -> buf1
            __syncthreads();
            if (t + 3 < KS) loadS(t + 3, 1);       // issue A(t+3)
            mstep(1, (t + 2 < KS) ? t + 2 : -1);
            if (t + 2 < KS) {
                writeS(0, 0);                      // A(t+2) from set A -> buf0
                __syncthreads();
            }
        }
    }

    // epilogue: C store (fp16, direct)
#pragma unroll
    for (int rg = 0; rg < 4; rg++)
#pragma unroll
        for (int nt = 0; nt < 4; nt++)
#pragma unroll
            for (int r = 0; r < 4; r++) {
                int row = m0 + rg * 16 + q * 4 + r;
                int col = n0 + nt * 16 + l15;
                C[(size_t)row * N + col] = f2hu(acc[rg][nt][r]);
            }
    // fused escore
    {
        const int head = n0 >> 6;
        float av[4];
#pragma unroll
        for (int nt = 0; nt < 4; nt++) av[nt] = att[head * 64 + nt * 16 + l15];
#pragma unroll
        for (int rg = 0; rg < 4; rg++)
#pragma unroll
            for (int r = 0; r < 4; r++) {
                float p = acc[rg][0][r] * av[0] + acc[rg][1][r] * av[1]
                        + acc[rg][2][r] * av[2] + acc[rg][3][r] * av[3];
#pragma unroll
                for (int off = 1; off < 16; off <<= 1) p += __shfl_xor(p, off);
                if (l15 == 0)
                    es_out[(size_t)(m0 + rg * 16 + q * 4 + r) * H + head] = p;
            }
    }
}

// ---------- layer-1 launch: GEMM + fill + ed1 (riders at grid tail) ----------
__global__ __launch_bounds__(256, 2)
void gemm1_fused(const void* __restrict__ Ax,
                 const unsigned short* __restrict__ Bp, unsigned short* __restrict__ C,
                 const float* __restrict__ att, float* __restrict__ es_out,
                 int MT, int NB, int N, int K, int H, int G1, int FB,
                 const int* sa1, const int* da1, const int* st1, int* cu1, int* cs1,
                 const int* sa2, const int* da2, const int* st2, int* cu2, int* cs2,
                 const float* __restrict__ xe, const float* __restrict__ v1dT,
                 float* __restrict__ ed1) {
    __shared__ alignas(16) _Float16 As[2][64][72];
    const int bid = blockIdx.x;
    if (bid < G1) gemm_core<false>(As, Ax, Bp, C, att, es_out, MT, NB, N, K, H, bid);
    else if (bid < G1 + FB) fill_core(bid - G1, sa1, da1, st1, cu1, cs1, sa2, da2, st2, cu2, cs2);
    else ed1_core(xe, v1dT, ed1, bid - G1 - FB);
}

// ---------- flat MLP core (64x64 tile, Bt3 bf16 hi/lo, fp32 A in-kernel split) ----------
__device__ __forceinline__ void flat_core(unsigned char* smemraw,
        const float* __restrict__ A, const unsigned short* __restrict__ Bt3,
        float* __restrict__ C, int mb) {
    const int K = 128, N = 64, KK = 384;
    auto As = (unsigned short (*)[64][72])smemraw;
    auto Bs = (unsigned short (*)[72])(smemraw + 18432);
    const int tid = threadIdx.x;
    const int wave = tid >> 6, lane = tid & 63;
    const int wr = wave >> 1, wc = wave & 1;
    const int quad = lane >> 4, l15 = lane & 15;
    const int m0 = mb * 64, n0 = 0;
    f32x4 acc[2][2] = {};
    for (int k0 = 0; k0 < KK; k0 += 64) {
        const int seg = k0 / K;
        const int ks = k0 - seg * K;
#pragma unroll
        for (int i = 0; i < 2; i++) {
            int idx = tid + i * 256;
            int r = idx >> 3, cv = (idx & 7) * 8;
            const float* ap = &A[(size_t)(m0 + r) * K + ks + cv];
            const float4 v0 = *(const float4*)ap;
            const float4 v1 = *(const float4*)(ap + 4);
            float va[8] = {v0.x, v0.y, v0.z, v0.w, v1.x, v1.y, v1.z, v1.w};
            short8 h8, l8;
#pragma unroll
            for (int j = 0; j < 8; j++) {
                unsigned short hh = f2bfu(va[j]);
                h8[j] = (short)hh;
                l8[j] = (short)f2bfu(va[j] - bfu2f(hh));
            }
            *(short8*)&As[0][r][cv] = h8;
            *(short8*)&As[1][r][cv] = l8;
            *(short8*)&Bs[r][cv] = *(const short8*)&Bt3[(size_t)(n0 + r) * KK + k0 + cv];
        }
        __syncthreads();
        const int abank = (seg < 2) ? 0 : 1;
#pragma unroll
        for (int kk = 0; kk < 64; kk += 32) {
            short8 a[2], b[2];
#pragma unroll
            for (int t = 0; t < 2; t++) {
                a[t] = *(const short8*)&As[abank][wr * 32 + t * 16 + l15][kk + quad * 8];
                b[t] = *(const short8*)&Bs[wc * 32 + t * 16 + l15][kk + quad * 8];
            }
#pragma unroll
            for (int mt = 0; mt < 2; mt++)
#pragma unroll
                for (int nt = 0; nt < 2; nt++)
                    acc[mt][nt] = __builtin_amdgcn_mfma_f32_16x16x32_bf16(
                        a[mt], b[nt], acc[mt][nt], 0, 0, 0);
        }
        __syncthreads();
    }
#pragma unroll
    for (int mt = 0; mt < 2; mt++)
#pragma unroll
        for (int nt = 0; nt < 2; nt++)
#pragma unroll
            for (int r = 0; r < 4; r++) {
                int row = m0 + wr * 32 + mt * 16 + quad * 4 + r;
                int col = n0 + wc * 32 + nt * 16 + l15;
                C[(size_t)row * N + col] = acc[mt][nt][r];
            }
}

// ---------- layer-2 launch: GEMM + flat MLP + ed2 (riders at grid tail) ----------
__global__ __launch_bounds__(256, 2)
void gemm2_fused(const void* __restrict__ Ax,
                 const unsigned short* __restrict__ Bp, unsigned short* __restrict__ C,
                 const float* __restrict__ att, float* __restrict__ es_out,
                 int MT, int NB, int N, int K, int H, int G2, int FLB,
                 const float* __restrict__ fA, const unsigned short* __restrict__ fBt3,
                 float* __restrict__ fC,
                 const unsigned short* __restrict__ x2h, const float* __restrict__ v2dT,
                 float* __restrict__ ed2) {
    __shared__ alignas(16) unsigned char smem[27648];
    const int bid = blockIdx.x;
    if (bid < G2) gemm_core<true>((_Float16(*)[64][72])smem, Ax, Bp, C, att, es_out,
                                  MT, NB, N, K, H, bid);
    else if (bid < G2 + FLB) flat_core(smem, fA, fBt3, fC, bid - G2);
    else ed2_core(x2h, v2dT, ed2, bid - G2 - FLB);
}

// ---------- GAT aggregate v3: csr-once + shfl distribution + fp16 dot2 gather ----------
// One wave per dst node. edh from precomputed edv (1 load). Neighbor list loaded once
// coalesced into regs (fast path n<=64 for H=8, n<=128 for H=4); alpha es loads batched;
// gather chunks software-pipelined with double reg-buffers; rows fp16, inner loop
// v_perm + v_dot2_f32_f16 (2 rows per op). FIN: fused output head.
template <int H, bool ELU, bool HOUT, bool FIN>
__global__ __launch_bounds__(256)
void gat_agg3(const int* __restrict__ csr, const int* __restrict__ rs,
              const unsigned short* __restrict__ hs,  // [Ns, H*64] fp16
              const float* __restrict__ es,           // [Ns, H]
              const float* __restrict__ edv,          // [Nd, H]
              const float* __restrict__ bias,
              void* __restrict__ out, int Nd,
              const float* __restrict__ fbuf, const float* __restrict__ flat_b,
              const float* __restrict__ last, const float* __restrict__ outW,
              const float* __restrict__ outb, float* __restrict__ fout) {
    constexpr int LH = (H == 8) ? 3 : 2;
    constexpr int EPC = 64 >> LH;          // rows per chunk: 8 (H=8) / 16 (H=4)
    constexpr int ND = H / 2;              // dwords per lane row-slice
    const int lane = threadIdx.x & 63;
    const int d = blockIdx.x * 4 + (threadIdx.x >> 6);
    if (d >= Nd) return;
    const int h = lane & (H - 1);
    const int e0 = lane >> LH;
    const int hB = lane >> (6 - LH);
    const float edh = edv[(size_t)d * H + h];
    const int beg = rs[d];
    const int deg = rs[d + 1] - beg;
    const int n = deg + 1;
    const int nch = (n + EPC - 1) / EPC;
    float acc[H] = {};
    const size_t rowoff = (size_t)lane * H;
    if (nch <= 8) {
        // --- neighbor indices: ONE coalesced load per wave ---
        int idxA = d, idxB = d;
        if (lane < deg) idxA = csr[beg + lane];
        if constexpr (H == 4) { if (64 + lane < deg) idxB = csr[beg + 64 + lane]; }
        // --- batched es loads (1 round trip) ---
        float av[8];
#pragma unroll
        for (int c = 0; c < 8; c++) {
            if (c < nch) {
                int jv = c * EPC + e0;
                int s;
                if (c * EPC + EPC - 1 < 64) s = __shfl(idxA, jv);
                else s = __shfl(idxB, jv - 64);
                av[c] = es[(size_t)s * H + h];
            }
        }
        // --- chunk row loads (pipelined, double reg buffer) ---
        unsigned rvA[EPC][ND], rvB[EPC][ND];
        auto loadChunk = [&](int c, unsigned (&rv)[EPC][ND]) {
#pragma unroll
            for (int u = 0; u < EPC; u++) {
                int src = c * EPC + u;
                int s = (src < 64) ? __shfl(idxA, src) : __shfl(idxB, src - 64);
                const unsigned short* rp = &hs[(size_t)s * (H * 64) + rowoff];
                if constexpr (H == 8) *(uint4v*)&rv[u][0] = *(const uint4v*)rp;
                else *(uint2v*)&rv[u][0] = *(const uint2v*)rp;
            }
        };
        loadChunk(0, rvA);   // overlaps softmax below
        // --- softmax from cached alphas ---
        float al[8], mx = -1e30f;
#pragma unroll
        for (int c = 0; c < 8; c++) {
            int jv = c * EPC + e0;
            float a = -1e30f;
            if (c < nch && jv < n) { a = av[c] + edh; a = (a > 0.f) ? a : 0.2f * a; }
            al[c] = a;
            mx = fmaxf(mx, a);
        }
#pragma unroll
        for (int off = H; off < 64; off <<= 1) mx = fmaxf(mx, __shfl_xor(mx, off));
        float exv[8], den = 0.f;
#pragma unroll
        for (int c = 0; c < 8; c++) { exv[c] = expf(al[c] - mx); den += exv[c]; }
#pragma unroll
        for (int off = H; off < 64; off <<= 1) den += __shfl_xor(den, off);
        const float inv = 1.f / den;
        float ec[8];
#pragma unroll
        for (int c = 0; c < 8; c++) ec[c] = exv[c] * inv;
        // --- gather: guard-free, paired-row dot2 ---
        auto computeChunk = [&](int c, unsigned (&rv)[EPC][ND]) {
#pragma unroll
            for (int pu = 0; pu < EPC / 2; pu++) {
                float w0 = __shfl(ec[c], (2 * pu) * H + hB);
                float w1 = __shfl(ec[c], (2 * pu + 1) * H + hB);
#ifdef USE_DOT2
                unsigned w2 = pkw(w0, w1);
#pragma unroll
                for (int dwi = 0; dwi < ND; dwi++) {
                    unsigned lo = __builtin_amdgcn_perm(rv[2 * pu + 1][dwi], rv[2 * pu][dwi], 0x05040100u);
                    unsigned hi = __builtin_amdgcn_perm(rv[2 * pu + 1][dwi], rv[2 * pu][dwi], 0x07060302u);
                    acc[2 * dwi] = fdot2acc(w2, lo, acc[2 * dwi]);
                    acc[2 * dwi + 1] = fdot2acc(w2, hi, acc[2 * dwi + 1]);
                }
#else
#pragma unroll
                for (int dwi = 0; dwi < ND; dwi++) {
                    unsigned q0 = rv[2 * pu][dwi], q1 = rv[2 * pu + 1][dwi];
                    acc[2 * dwi]     += w0 * hu2f((unsigned short)(q0 & 0xffff))
                                      + w1 * hu2f((unsigned short)(q1 & 0xffff));
                    acc[2 * dwi + 1] += w0 * hu2f((unsigned short)(q0 >> 16))
                                      + w1 * hu2f((unsigned short)(q1 >> 16));
                }
#endif
            }
        };
#pragma unroll
        for (int c = 0; c < 8; c += 2) {
            if (c >= nch) break;
            if (c + 1 < nch) loadChunk(c + 1, rvB);
            computeChunk(c, rvA);
            if (c + 1 >= nch) break;
            if (c + 2 < nch) loadChunk(c + 2, rvA);
            computeChunk(c + 1, rvB);
        }
    } else {
        // fallback two-pass (very rare large-degree nodes)
        float mx = -1e30f;
        for (int j0 = 0; j0 < n; j0 += EPC) {
            int j = j0 + e0;
            if (j < n) {
                int s = (j < deg) ? csr[beg + j] : d;
                float a = es[(size_t)s * H + h] + edh;
                a = (a > 0.0f) ? a : 0.2f * a;
                mx = fmaxf(mx, a);
            }
        }
#pragma unroll
        for (int off = H; off < 64; off <<= 1) mx = fmaxf(mx, __shfl_xor(mx, off));
        float den = 0.0f;
        for (int j0 = 0; j0 < n; j0 += EPC) {
            int j = j0 + e0;
            if (j < n) {
                int s = (j < deg) ? csr[beg + j] : d;
                float a = es[(size_t)s * H + h] + edh;
                a = (a > 0.0f) ? a : 0.2f * a;
                den += expf(a - mx);
            }
        }
#pragma unroll
        for (int off = H; off < 64; off <<= 1) den += __shfl_xor(den, off);
        const float inv = 1.0f / den;
        const float mB = __shfl(mx, hB);
        const float invB = __shfl(inv, hB);
        const float edhB = __shfl(edh, hB);
        for (int j = 0; j < n; j++) {
            int s = (j < deg) ? csr[beg + j] : d;
            const unsigned short* rp = &hs[(size_t)s * (H * 64) + rowoff];
            float a = es[(size_t)s * H + hB] + edhB;
            a = (a > 0.0f) ? a : 0.2f * a;
            float w = expf(a - mB) * invB;
#pragma unroll
            for (int k = 0; k < H; k++) acc[k] += w * hu2f(rp[k]);
        }
    }
    if constexpr (FIN) {
        float f4[4];
#pragma unroll
        for (int k = 0; k < 4; k++) {
            float a2v = acc[k] + __shfl_xor(acc[k], 32);
            f4[k] = a2v + __shfl_xor(a2v, 16);
        }
        float part = 0.f;
        if (lane < 16) {
            const int c0 = lane * 4;
            float4 fb4 = *(const float4*)&fbuf[(size_t)d * 64 + c0];
            float4 lb4 = *(const float4*)&last[(size_t)d * 64 + c0];
            const float* fbv = &fb4.x;
            const float* lbv = &lb4.x;
#pragma unroll
            for (int k = 0; k < 4; k++) {
                int c = c0 + k;
                float h2 = 0.25f * f4[k] + bias[c];
                part += h2 * outW[c];
                part += (fbv[k] + flat_b[c]) * outW[64 + c];
                part += lbv[k] * outW[128 + c];
            }
        }
#pragma unroll
        for (int off = 1; off < 16; off <<= 1) part += __shfl_xor(part, off);
        if (lane == 0) fout[d] = part + outb[0];
    } else {
#pragma unroll
        for (int k = 0; k < H; k++) {
            float v = acc[k];
            if (ELU) {
                v += bias[lane * H + k];
                v = (v > 0.0f) ? v : expm1f(v);
            }
            acc[k] = v;
        }
        if constexpr (HOUT) {
            half8 hv;
#pragma unroll
            for (int k = 0; k < H; k++) hv[k] = (_Float16)acc[k];
            _Float16* op = (_Float16*)out + (size_t)d * (H * 64) + rowoff;
            *(half8*)op = hv;
        } else {
            float* op = (float*)out + (size_t)d * (H * 64) + rowoff;
#pragma unroll
            for (int qd = 0; qd < H / 4; qd++)
                *(float4*)&op[qd * 4] = *(float4*)&acc[qd * 4];
        }
    }
}

extern "C" void kernel_launch(void* const* d_in, const int* in_sizes, int n_in,
                              void* d_out, int out_size, void* d_ws, size_t ws_size,
                              hipStream_t stream) {
    const float* x    = (const float*)d_in[0];
    const float* flat = (const float*)d_in[1];
    const float* last = (const float*)d_in[2];
    const int*  es1i  = (const int*)d_in[3];
    const int*  ed1i  = (const int*)d_in[4];
    const int*  es2i  = (const int*)d_in[5];
    const int*  ed2i  = (const int*)d_in[6];
    const float* W1s  = (const float*)d_in[7];
    const float* W1d  = (const float*)d_in[8];
    const float* a1s  = (const float*)d_in[9];
    const float* a1d  = (const float*)d_in[10];
    const float* b1   = (const float*)d_in[11];
    const float* W2s  = (const float*)d_in[12];
    const float* W2d  = (const float*)d_in[13];
    const float* a2s  = (const float*)d_in[14];
    const float* a2d  = (const float*)d_in[15];
    const float* b2   = (const float*)d_in[16];
    const float* fW   = (const float*)d_in[17];
    const float* fb   = (const float*)d_in[18];
    const float* oW   = (const float*)d_in[19];
    const float* ob   = (const float*)d_in[20];
    float* out = (float*)d_out;

    float* ws = (float*)d_ws;
    // ---- layout (float-element offsets; proven footprint) ----
    unsigned short* hs1_h = (unsigned short*)ws;                   // [80000][512] fp16
    float* es1f = ws + 24576000;                                   // [80000][8]
    float* ed1f = ws + 25216000;                                   // [16000][8]
    float* acc1 = ws + 25344000;                                   // L1 out, fp16 [16000][512]
    unsigned short* wb = (unsigned short*)(ws + 54016000);
    unsigned short* w1s_pk = wb;                                   // 131072 us
    unsigned short* w2s_pk = wb + 524288;                          // 131072 us
    unsigned short* fw_t3  = wb + 1048576;                         // 24576 us
    float* v1dT = ws + 54600000;                                   // 2048
    float* v2dT = ws + 54602048;                                   // 2048
    int* ibase   = (int*)(ws + 54816000);
    int* cnt1    = ibase;
    int* cursor1 = ibase + 16000;
    int* cnt2    = ibase + 32000;
    int* cursor2 = ibase + 36096;
    int* start1  = ibase + 40192;
    int* start2  = ibase + 56193;
    int* csr1    = ibase + 60290;
    int* csr2    = ibase + 316290;
    const size_t NEED = ((size_t)54816000 + 381826) * 4;
    if (ws_size < NEED) {
        fprintf(stderr, "kernel_launch: ws_size %zu < needed %zu\n", ws_size, NEED);
        return;
    }
    unsigned short* hs2_h = (unsigned short*)ws;                   // [16000][256] fp16
    float* es2f = ws + 2572288;
    float* ed2f = ws + 2636288;                                    // [4096][4]
    float* fbuf = ws + 3701248;
    unsigned short* acc1h = (unsigned short*)acc1;

    // ---- zero counters/cursors, then prep+hist (1 launch) + scan ----
    (void)hipMemsetAsync(ibase, 0, 40192 * sizeof(int), stream);
    {
        const int PB = 1072;   // (131072+131072+8192+4096)/256
        const int HB = (E1 + E2) / 256;   // 1256
        prep_hist<<<PB + HB, 256, 0, stream>>>(
            W1s, w1s_pk, W2s, w2s_pk,
            W1d, a1d, v1dT, W2d, a2d, v2dT,
            fW, fw_t3, PB, ed1i, cnt1, ed2i, cnt2);
    }
    scan_dual<<<2, 1024, 0, stream>>>(cnt1, start1, N2, cnt2, start2, N3);

    // ---- layer 1 GEMM + CSR fill + ed1 in one launch (riders at tail) ----
    {
        const int MT = N1 / 64;             // 1250
        const int NB = 2;
        const int G1 = 8 * NB * ((MT + 7) / 8);   // 2512
        const int FB = (E1 + E2) / 256;           // 1256
        const int EB = N2 / 16;                   // 1000
        gemm1_fused<<<G1 + FB + EB, 256, 0, stream>>>(
            x, w1s_pk, hs1_h, a1s, es1f, MT, NB, 512, 256, 8, G1, FB,
            es1i, ed1i, start1, cursor1, csr1, es2i, ed2i, start2, cursor2, csr2,
            x, v1dT, ed1f);
    }
    gat_agg3<8, true, true, false><<<N2 / 4, 256, 0, stream>>>(
        csr1, start1, hs1_h, es1f, ed1f, b1, acc1h, N2,
        nullptr, nullptr, nullptr, nullptr, nullptr, nullptr);

    // ---- layer 2 GEMM + flat MLP + ed2 in one launch (riders at tail) ----
    {
        const int MT = N2 / 64;             // 250
        const int G2 = 8 * ((MT + 7) / 8);  // 256
        const int FLB = N3 / 64;            // 64
        const int EB2 = N3 / 16;            // 256
        gemm2_fused<<<G2 + FLB + EB2, 256, 0, stream>>>(
            acc1h, w2s_pk, hs2_h, a2s, es2f, MT, 1, 256, 512, 4, G2, FLB,
            flat, fw_t3, fbuf,
            acc1h, v2dT, ed2f);
    }
    // ---- fused agg2 + output head ----
    gat_agg3<4, false, false, true><<<N3 / 4, 256, 0, stream>>>(
        csr2, start2, hs2_h, es2f, ed2f, b2, nullptr, N3,
        fbuf, fb, last, oW, ob, out);
}